// Round 1
// baseline (872.280 us; speedup 1.0000x reference)
//
#include <hip/hip_runtime.h>
#include <math.h>

#define NSLOPE 0.2f

__device__ __forceinline__ float lrelu(float x){ return x > 0.f ? x : NSLOPE * x; }
__device__ __forceinline__ float eluf(float x){ return x > 0.f ? x : expm1f(x); }

// ---------------- GEMM1: h1[N,256] = x[N,256] @ W1[256,256] ----------------
// 64 rows x 256 cols per block, 256 threads, 8x8 register tile per thread.
__global__ __launch_bounds__(256) void gemm1_kernel(const float* __restrict__ x,
                                                    const float* __restrict__ W,
                                                    float* __restrict__ h1, int N) {
  __shared__ __align__(16) float xsT[16][68];   // [k][row], padded
  __shared__ __align__(16) float ws[16][260];   // [k][col], padded
  int tid = threadIdx.x;
  int tx = tid & 31, ty = tid >> 5;
  int row0 = blockIdx.x * 64;
  float acc[8][8];
#pragma unroll
  for (int i = 0; i < 8; ++i)
#pragma unroll
    for (int j = 0; j < 8; ++j) acc[i][j] = 0.f;

  int lr = tid >> 2;         // row 0..63 for x staging
  int lk = (tid & 3) * 4;    // k offset 0,4,8,12

  for (int kc = 0; kc < 256; kc += 16) {
    int r = row0 + lr;
    float4 xv = make_float4(0.f, 0.f, 0.f, 0.f);
    if (r < N) xv = *(const float4*)(x + (size_t)r * 256 + kc + lk);
    xsT[lk + 0][lr] = xv.x; xsT[lk + 1][lr] = xv.y;
    xsT[lk + 2][lr] = xv.z; xsT[lk + 3][lr] = xv.w;
#pragma unroll
    for (int j = 0; j < 16; ++j) ws[j][tid] = W[(size_t)(kc + j) * 256 + tid];
    __syncthreads();
#pragma unroll
    for (int kk = 0; kk < 16; ++kk) {
      float a[8], b[8];
#pragma unroll
      for (int i = 0; i < 8; ++i) a[i] = xsT[kk][ty * 8 + i];
#pragma unroll
      for (int j = 0; j < 8; ++j) b[j] = ws[kk][tx * 8 + j];
#pragma unroll
      for (int i = 0; i < 8; ++i)
#pragma unroll
        for (int j = 0; j < 8; ++j) acc[i][j] = fmaf(a[i], b[j], acc[i][j]);
    }
    __syncthreads();
  }
#pragma unroll
  for (int i = 0; i < 8; ++i) {
    int r = row0 + ty * 8 + i;
    if (r < N) {
      float4 v0 = make_float4(acc[i][0], acc[i][1], acc[i][2], acc[i][3]);
      float4 v1 = make_float4(acc[i][4], acc[i][5], acc[i][6], acc[i][7]);
      *(float4*)(h1 + (size_t)r * 256 + tx * 8) = v0;
      *(float4*)(h1 + (size_t)r * 256 + tx * 8 + 4) = v1;
    }
  }
}

// ---------------- att1: a_src/a_dst [N,8] ----------------
__global__ __launch_bounds__(256) void att1_kernel(const float* __restrict__ h1,
                                                   const float* __restrict__ att_src,
                                                   const float* __restrict__ att_dst,
                                                   float* __restrict__ a_src,
                                                   float* __restrict__ a_dst, int N) {
  __shared__ __align__(16) float sas[256];
  __shared__ __align__(16) float sad[256];
  int tid = threadIdx.x;
  sas[tid] = att_src[tid];
  sad[tid] = att_dst[tid];
  __syncthreads();
  int gid = blockIdx.x * 256 + tid;
  if (gid >= N * 8) return;
  int h = gid & 7;
  const float4* hv = (const float4*)(h1 + (size_t)(gid >> 3) * 256 + h * 32);
  const float4* a4 = (const float4*)(sas + h * 32);
  const float4* d4 = (const float4*)(sad + h * 32);
  float s1 = 0.f, s2 = 0.f;
#pragma unroll
  for (int j = 0; j < 8; ++j) {
    float4 v = hv[j], a = a4[j], d = d4[j];
    s1 += v.x * a.x + v.y * a.y + v.z * a.z + v.w * a.w;
    s2 += v.x * d.x + v.y * d.y + v.z * d.z + v.w * d.w;
  }
  a_src[gid] = s1;
  a_dst[gid] = s2;
}

// ---------------- CSR build ----------------
__global__ void count_kernel(const int* __restrict__ ei, int* __restrict__ cnt, int E, int N) {
  int e = blockIdx.x * 256 + threadIdx.x;
  if (e >= E + N) return;
  int d = (e < E) ? ei[E + e] : (e - E);
  atomicAdd(&cnt[d], 1);
}

__global__ __launch_bounds__(256) void scan1_kernel(const int* __restrict__ cnt,
                                                    int* __restrict__ tmp,
                                                    int* __restrict__ bsum, int N) {
  __shared__ int sh[256];
  int t = threadIdx.x;
  int base = blockIdx.x * 1024 + t * 4;
  int v[4]; int s = 0;
#pragma unroll
  for (int j = 0; j < 4; ++j) { v[j] = (base + j < N) ? cnt[base + j] : 0; s += v[j]; }
  sh[t] = s;
  __syncthreads();
  for (int off = 1; off < 256; off <<= 1) {
    int xv = (t >= off) ? sh[t - off] : 0;
    __syncthreads();
    sh[t] += xv;
    __syncthreads();
  }
  if (t == 255) bsum[blockIdx.x] = sh[255];
  int run = sh[t] - s;  // exclusive
#pragma unroll
  for (int j = 0; j < 4; ++j) {
    if (base + j < N) tmp[base + j] = run;
    run += v[j];
  }
}

__global__ __launch_bounds__(128) void scan2_kernel(const int* __restrict__ bsum,
                                                    int* __restrict__ boff, int nb) {
  __shared__ int sh[128];
  int t = threadIdx.x;
  int v = (t < nb) ? bsum[t] : 0;
  sh[t] = v;
  __syncthreads();
  for (int off = 1; off < 128; off <<= 1) {
    int xv = (t >= off) ? sh[t - off] : 0;
    __syncthreads();
    sh[t] += xv;
    __syncthreads();
  }
  if (t < nb) boff[t] = sh[t] - v;
}

__global__ void scan3_kernel(const int* __restrict__ tmp, const int* __restrict__ boff,
                             int* __restrict__ row_ptr, int* __restrict__ cursor,
                             int N, int Etot) {
  int i = blockIdx.x * 256 + threadIdx.x;
  if (i == 0) row_ptr[N] = Etot;
  if (i >= N) return;
  int rp = tmp[i] + boff[i >> 10];
  row_ptr[i] = rp;
  cursor[i] = rp;
}

__global__ void fill_kernel(const int* __restrict__ ei, int* __restrict__ cursor,
                            int* __restrict__ col, int E, int N) {
  int e = blockIdx.x * 256 + threadIdx.x;
  if (e >= E + N) return;
  int s, d;
  if (e < E) { s = ei[e]; d = ei[E + e]; } else { s = e - E; d = s; }
  int pos = atomicAdd(&cursor[d], 1);
  col[pos] = s;
}

// ---------------- agg1: wave per node, 8 heads x 32 ch ----------------
__global__ __launch_bounds__(256) void agg1_kernel(const float* __restrict__ h1,
                                                   const float* __restrict__ a_src,
                                                   const float* __restrict__ a_dst,
                                                   const int* __restrict__ row_ptr,
                                                   const int* __restrict__ col,
                                                   const float* __restrict__ b1,
                                                   float* __restrict__ hmid, int N) {
  int lane = threadIdx.x & 63;
  int n = blockIdx.x * 4 + (threadIdx.x >> 6);
  if (n >= N) return;
  int beg = row_ptr[n], deg = row_ptr[n + 1] - beg;

  int hA = lane & 7, eoA = lane >> 3;
  float adst = a_dst[n * 8 + hA];
  float mx = -1e30f;
  for (int e0 = 0; e0 < deg; e0 += 8) {
    int e = e0 + eoA;
    if (e < deg) {
      int s = col[beg + e];
      mx = fmaxf(mx, lrelu(a_src[s * 8 + hA] + adst));
    }
  }
#pragma unroll
  for (int off = 8; off < 64; off <<= 1) mx = fmaxf(mx, __shfl_xor(mx, off));
  float sum = 0.f;
  for (int e0 = 0; e0 < deg; e0 += 8) {
    int e = e0 + eoA;
    if (e < deg) {
      int s = col[beg + e];
      sum += __expf(lrelu(a_src[s * 8 + hA] + adst) - mx);
    }
  }
#pragma unroll
  for (int off = 8; off < 64; off <<= 1) sum += __shfl_xor(sum, off);
  float invden = 1.f / (sum + 1e-16f);

  int hB = lane >> 3;                 // head owning channels lane*4..lane*4+3
  float mB   = __shfl(mx, hB);
  float invB = __shfl(invden, hB);
  float adB  = __shfl(adst, hB);

  float4 acc = make_float4(0.f, 0.f, 0.f, 0.f);
  const float4* h1v = (const float4*)h1;
  for (int e = 0; e < deg; ++e) {
    int s = col[beg + e];
    float v = lrelu(a_src[s * 8 + hB] + adB);
    float al = __expf(v - mB) * invB;
    float4 hv = h1v[(size_t)s * 64 + lane];
    acc.x = fmaf(al, hv.x, acc.x);
    acc.y = fmaf(al, hv.y, acc.y);
    acc.z = fmaf(al, hv.z, acc.z);
    acc.w = fmaf(al, hv.w, acc.w);
  }
  float4 bb = ((const float4*)b1)[lane];
  acc.x = eluf(acc.x + bb.x);
  acc.y = eluf(acc.y + bb.y);
  acc.z = eluf(acc.z + bb.z);
  acc.w = eluf(acc.w + bb.w);
  ((float4*)hmid)[(size_t)n * 64 + lane] = acc;
}

// ---------------- GEMM2 + att2 fused: h2[N,40], a_src2/a_dst2[N] ----------------
__global__ __launch_bounds__(256) void gemm2_kernel(const float* __restrict__ hmid,
                                                    const float* __restrict__ W2,
                                                    const float* __restrict__ as2,
                                                    const float* __restrict__ ad2,
                                                    float* __restrict__ h2,
                                                    float* __restrict__ a_src2,
                                                    float* __restrict__ a_dst2, int N) {
  __shared__ float W2s[256 * 40];
  __shared__ __align__(16) float rowbuf[4][256];
  __shared__ float asv[40], adv[40];
  int tid = threadIdx.x;
  for (int i = tid; i < 256 * 40; i += 256) W2s[i] = W2[i];
  if (tid < 40) { asv[tid] = as2[tid]; adv[tid] = ad2[tid]; }
  __syncthreads();
  int wv = tid >> 6, lane = tid & 63;
  int n = blockIdx.x * 4 + wv;
  if (n < N) {
    ((float4*)rowbuf[wv])[lane] = ((const float4*)hmid)[(size_t)n * 64 + lane];
  }
  __syncthreads();
  if (n >= N) return;
  float acc = 0.f;
  if (lane < 40) {
    const float4* rv = (const float4*)rowbuf[wv];
#pragma unroll 4
    for (int k4 = 0; k4 < 64; ++k4) {
      float4 r = rv[k4];
      int kb = k4 * 4;
      acc = fmaf(r.x, W2s[(kb + 0) * 40 + lane], acc);
      acc = fmaf(r.y, W2s[(kb + 1) * 40 + lane], acc);
      acc = fmaf(r.z, W2s[(kb + 2) * 40 + lane], acc);
      acc = fmaf(r.w, W2s[(kb + 3) * 40 + lane], acc);
    }
  }
  float vs = (lane < 40) ? acc * asv[lane] : 0.f;
  float vd = (lane < 40) ? acc * adv[lane] : 0.f;
#pragma unroll
  for (int off = 1; off < 64; off <<= 1) {
    vs += __shfl_xor(vs, off);
    vd += __shfl_xor(vd, off);
  }
  if (lane < 40) h2[(size_t)n * 40 + lane] = acc;
  if (lane == 0) { a_src2[n] = vs; a_dst2[n] = vd; }
}

// ---------------- agg2: wave per node, 1 head x 40 ch ----------------
__global__ __launch_bounds__(256) void agg2_kernel(const float* __restrict__ h2,
                                                   const float* __restrict__ a_src,
                                                   const float* __restrict__ a_dst,
                                                   const int* __restrict__ row_ptr,
                                                   const int* __restrict__ col,
                                                   const float* __restrict__ b2,
                                                   float* __restrict__ out, int N) {
  int lane = threadIdx.x & 63;
  int n = blockIdx.x * 4 + (threadIdx.x >> 6);
  if (n >= N) return;
  int beg = row_ptr[n], deg = row_ptr[n + 1] - beg;
  float adst = a_dst[n];
  float mx = -1e30f;
  for (int e0 = 0; e0 < deg; e0 += 64) {
    int e = e0 + lane;
    if (e < deg) mx = fmaxf(mx, lrelu(a_src[col[beg + e]] + adst));
  }
#pragma unroll
  for (int off = 1; off < 64; off <<= 1) mx = fmaxf(mx, __shfl_xor(mx, off));
  float sum = 0.f;
  for (int e0 = 0; e0 < deg; e0 += 64) {
    int e = e0 + lane;
    if (e < deg) sum += __expf(lrelu(a_src[col[beg + e]] + adst) - mx);
  }
#pragma unroll
  for (int off = 1; off < 64; off <<= 1) sum += __shfl_xor(sum, off);
  float invden = 1.f / (sum + 1e-16f);
  float acc = 0.f;
  for (int e = 0; e < deg; ++e) {
    int s = col[beg + e];
    float al = __expf(lrelu(a_src[s] + adst) - mx) * invden;
    if (lane < 40) acc = fmaf(al, h2[(size_t)s * 40 + lane], acc);
  }
  if (lane < 40) out[(size_t)n * 40 + lane] = acc + b2[lane];
}

extern "C" void kernel_launch(void* const* d_in, const int* in_sizes, int n_in,
                              void* d_out, int out_size, void* d_ws, size_t ws_size,
                              hipStream_t stream) {
  const float* x   = (const float*)d_in[0];
  const int*   ei  = (const int*)d_in[1];
  const float* W1  = (const float*)d_in[2];
  const float* as1 = (const float*)d_in[3];
  const float* ad1 = (const float*)d_in[4];
  const float* b1  = (const float*)d_in[5];
  const float* W2  = (const float*)d_in[6];
  const float* as2 = (const float*)d_in[7];
  const float* ad2 = (const float*)d_in[8];
  const float* b2  = (const float*)d_in[9];
  float* out = (float*)d_out;

  int N = in_sizes[0] / 256;
  int E = in_sizes[1] / 2;
  int Etot = E + N;

  char* p = (char*)d_ws;
  auto alloc = [&](size_t bytes) -> char* {
    char* r = p;
    p += (bytes + 255) & ~(size_t)255;
    return r;
  };
  float* h1     = (float*)alloc((size_t)N * 256 * 4);
  float* hmid   = (float*)alloc((size_t)N * 256 * 4);
  float* a_src1 = (float*)alloc((size_t)N * 8 * 4);
  float* a_dst1 = (float*)alloc((size_t)N * 8 * 4);
  float* h2     = (float*)alloc((size_t)N * 40 * 4);
  float* a_src2 = (float*)alloc((size_t)N * 4);
  float* a_dst2 = (float*)alloc((size_t)N * 4);
  int* cnt      = (int*)alloc((size_t)N * 4);
  int* cursor   = (int*)alloc((size_t)N * 4);
  int* row_ptr  = (int*)alloc(((size_t)N + 1) * 4);
  int* tmp      = (int*)alloc((size_t)N * 4);
  int* bsum     = (int*)alloc(512);
  int* boff     = (int*)alloc(512);
  int* colx     = (int*)alloc((size_t)Etot * 4);

  hipMemsetAsync(cnt, 0, (size_t)N * 4, stream);

  int nbE = (Etot + 255) / 256;
  int nb1 = (N + 1023) / 1024;
  count_kernel<<<nbE, 256, 0, stream>>>(ei, cnt, E, N);
  scan1_kernel<<<nb1, 256, 0, stream>>>(cnt, tmp, bsum, N);
  scan2_kernel<<<1, 128, 0, stream>>>(bsum, boff, nb1);
  scan3_kernel<<<(N + 255) / 256, 256, 0, stream>>>(tmp, boff, row_ptr, cursor, N, Etot);
  fill_kernel<<<nbE, 256, 0, stream>>>(ei, cursor, colx, E, N);

  gemm1_kernel<<<(N + 63) / 64, 256, 0, stream>>>(x, W1, h1, N);
  att1_kernel<<<(N * 8 + 255) / 256, 256, 0, stream>>>(h1, as1, ad1, a_src1, a_dst1, N);
  agg1_kernel<<<(N + 3) / 4, 256, 0, stream>>>(h1, a_src1, a_dst1, row_ptr, colx, b1, hmid, N);
  gemm2_kernel<<<(N + 3) / 4, 256, 0, stream>>>(hmid, W2, as2, ad2, h2, a_src2, a_dst2, N);
  agg2_kernel<<<(N + 3) / 4, 256, 0, stream>>>(h2, a_src2, a_dst2, row_ptr, colx, b2, out, N);
}

// Round 2
// 742.385 us; speedup vs baseline: 1.1750x; 1.1750x over previous
//
#include <hip/hip_runtime.h>
#include <math.h>

#define NSLOPE 0.2f

__device__ __forceinline__ float lrelu(float x){ return x > 0.f ? x : NSLOPE * x; }
__device__ __forceinline__ float eluf(float x){ return x > 0.f ? x : expm1f(x); }

// ---------------- GEMM1: h1[N,256] = x[N,256] @ W1[256,256] ----------------
// 64 rows x 256 cols per block, 256 threads, 8x8 register tile per thread.
__global__ __launch_bounds__(256) void gemm1_kernel(const float* __restrict__ x,
                                                    const float* __restrict__ W,
                                                    float* __restrict__ h1, int N) {
  __shared__ __align__(16) float xsT[16][68];   // [k][row], padded
  __shared__ __align__(16) float ws[16][260];   // [k][col], padded
  int tid = threadIdx.x;
  int tx = tid & 31, ty = tid >> 5;
  int row0 = blockIdx.x * 64;
  float acc[8][8];
#pragma unroll
  for (int i = 0; i < 8; ++i)
#pragma unroll
    for (int j = 0; j < 8; ++j) acc[i][j] = 0.f;

  int lr = tid >> 2;         // row 0..63 for x staging
  int lk = (tid & 3) * 4;    // k offset 0,4,8,12

  for (int kc = 0; kc < 256; kc += 16) {
    int r = row0 + lr;
    float4 xv = make_float4(0.f, 0.f, 0.f, 0.f);
    if (r < N) xv = *(const float4*)(x + (size_t)r * 256 + kc + lk);
    xsT[lk + 0][lr] = xv.x; xsT[lk + 1][lr] = xv.y;
    xsT[lk + 2][lr] = xv.z; xsT[lk + 3][lr] = xv.w;
#pragma unroll
    for (int j = 0; j < 16; ++j) ws[j][tid] = W[(size_t)(kc + j) * 256 + tid];
    __syncthreads();
#pragma unroll
    for (int kk = 0; kk < 16; ++kk) {
      float a[8], b[8];
#pragma unroll
      for (int i = 0; i < 8; ++i) a[i] = xsT[kk][ty * 8 + i];
#pragma unroll
      for (int j = 0; j < 8; ++j) b[j] = ws[kk][tx * 8 + j];
#pragma unroll
      for (int i = 0; i < 8; ++i)
#pragma unroll
        for (int j = 0; j < 8; ++j) acc[i][j] = fmaf(a[i], b[j], acc[i][j]);
    }
    __syncthreads();
  }
#pragma unroll
  for (int i = 0; i < 8; ++i) {
    int r = row0 + ty * 8 + i;
    if (r < N) {
      float4 v0 = make_float4(acc[i][0], acc[i][1], acc[i][2], acc[i][3]);
      float4 v1 = make_float4(acc[i][4], acc[i][5], acc[i][6], acc[i][7]);
      *(float4*)(h1 + (size_t)r * 256 + tx * 8) = v0;
      *(float4*)(h1 + (size_t)r * 256 + tx * 8 + 4) = v1;
    }
  }
}

// ---------------- att1: a_src/a_dst [N,8] ----------------
__global__ __launch_bounds__(256) void att1_kernel(const float* __restrict__ h1,
                                                   const float* __restrict__ att_src,
                                                   const float* __restrict__ att_dst,
                                                   float* __restrict__ a_src,
                                                   float* __restrict__ a_dst, int N) {
  __shared__ __align__(16) float sas[256];
  __shared__ __align__(16) float sad[256];
  int tid = threadIdx.x;
  sas[tid] = att_src[tid];
  sad[tid] = att_dst[tid];
  __syncthreads();
  int gid = blockIdx.x * 256 + tid;
  if (gid >= N * 8) return;
  int h = gid & 7;
  const float4* hv = (const float4*)(h1 + (size_t)(gid >> 3) * 256 + h * 32);
  const float4* a4 = (const float4*)(sas + h * 32);
  const float4* d4 = (const float4*)(sad + h * 32);
  float s1 = 0.f, s2 = 0.f;
#pragma unroll
  for (int j = 0; j < 8; ++j) {
    float4 v = hv[j], a = a4[j], d = d4[j];
    s1 += v.x * a.x + v.y * a.y + v.z * a.z + v.w * a.w;
    s2 += v.x * d.x + v.y * d.y + v.z * d.z + v.w * d.w;
  }
  a_src[gid] = s1;
  a_dst[gid] = s2;
}

// ---------------- CSR build ----------------
__global__ void count_kernel(const int* __restrict__ ei, int* __restrict__ cnt, int E, int N) {
  int e = blockIdx.x * 256 + threadIdx.x;
  if (e >= E + N) return;
  int d = (e < E) ? ei[E + e] : (e - E);
  atomicAdd(&cnt[d], 1);
}

__global__ __launch_bounds__(256) void scan1_kernel(const int* __restrict__ cnt,
                                                    int* __restrict__ tmp,
                                                    int* __restrict__ bsum, int N) {
  __shared__ int sh[256];
  int t = threadIdx.x;
  int base = blockIdx.x * 1024 + t * 4;
  int v[4]; int s = 0;
#pragma unroll
  for (int j = 0; j < 4; ++j) { v[j] = (base + j < N) ? cnt[base + j] : 0; s += v[j]; }
  sh[t] = s;
  __syncthreads();
  for (int off = 1; off < 256; off <<= 1) {
    int xv = (t >= off) ? sh[t - off] : 0;
    __syncthreads();
    sh[t] += xv;
    __syncthreads();
  }
  if (t == 255) bsum[blockIdx.x] = sh[255];
  int run = sh[t] - s;  // exclusive
#pragma unroll
  for (int j = 0; j < 4; ++j) {
    if (base + j < N) tmp[base + j] = run;
    run += v[j];
  }
}

__global__ __launch_bounds__(128) void scan2_kernel(const int* __restrict__ bsum,
                                                    int* __restrict__ boff, int nb) {
  __shared__ int sh[128];
  int t = threadIdx.x;
  int v = (t < nb) ? bsum[t] : 0;
  sh[t] = v;
  __syncthreads();
  for (int off = 1; off < 128; off <<= 1) {
    int xv = (t >= off) ? sh[t - off] : 0;
    __syncthreads();
    sh[t] += xv;
    __syncthreads();
  }
  if (t < nb) boff[t] = sh[t] - v;
}

__global__ void scan3_kernel(const int* __restrict__ tmp, const int* __restrict__ boff,
                             int* __restrict__ row_ptr, int* __restrict__ cursor,
                             int N, int Etot) {
  int i = blockIdx.x * 256 + threadIdx.x;
  if (i == 0) row_ptr[N] = Etot;
  if (i >= N) return;
  int rp = tmp[i] + boff[i >> 10];
  row_ptr[i] = rp;
  cursor[i] = rp;
}

__global__ void fill_kernel(const int* __restrict__ ei, int* __restrict__ cursor,
                            int* __restrict__ col, int E, int N) {
  int e = blockIdx.x * 256 + threadIdx.x;
  if (e >= E + N) return;
  int s, d;
  if (e < E) { s = ei[e]; d = ei[E + e]; } else { s = e - E; d = s; }
  int pos = atomicAdd(&cursor[d], 1);
  col[pos] = s;
}

// ---------------- agg1: wave per node, 8 heads x 32 ch ----------------
__global__ __launch_bounds__(256) void agg1_kernel(const float* __restrict__ h1,
                                                   const float* __restrict__ a_src,
                                                   const float* __restrict__ a_dst,
                                                   const int* __restrict__ row_ptr,
                                                   const int* __restrict__ col,
                                                   const float* __restrict__ b1,
                                                   float* __restrict__ hmid, int N) {
  int lane = threadIdx.x & 63;
  int n = blockIdx.x * 4 + (threadIdx.x >> 6);
  if (n >= N) return;
  int beg = row_ptr[n], deg = row_ptr[n + 1] - beg;

  int hA = lane & 7, eoA = lane >> 3;
  float adst = a_dst[n * 8 + hA];
  float mx = -1e30f;
  for (int e0 = 0; e0 < deg; e0 += 8) {
    int e = e0 + eoA;
    if (e < deg) {
      int s = col[beg + e];
      mx = fmaxf(mx, lrelu(a_src[s * 8 + hA] + adst));
    }
  }
#pragma unroll
  for (int off = 8; off < 64; off <<= 1) mx = fmaxf(mx, __shfl_xor(mx, off));
  float sum = 0.f;
  for (int e0 = 0; e0 < deg; e0 += 8) {
    int e = e0 + eoA;
    if (e < deg) {
      int s = col[beg + e];
      sum += __expf(lrelu(a_src[s * 8 + hA] + adst) - mx);
    }
  }
#pragma unroll
  for (int off = 8; off < 64; off <<= 1) sum += __shfl_xor(sum, off);
  float invden = 1.f / (sum + 1e-16f);

  int hB = lane >> 3;                 // head owning channels lane*4..lane*4+3
  float mB   = __shfl(mx, hB);
  float invB = __shfl(invden, hB);
  float adB  = __shfl(adst, hB);

  float4 acc = make_float4(0.f, 0.f, 0.f, 0.f);
  const float4* h1v = (const float4*)h1;
  for (int e = 0; e < deg; ++e) {
    int s = col[beg + e];
    float v = lrelu(a_src[s * 8 + hB] + adB);
    float al = __expf(v - mB) * invB;
    float4 hv = h1v[(size_t)s * 64 + lane];
    acc.x = fmaf(al, hv.x, acc.x);
    acc.y = fmaf(al, hv.y, acc.y);
    acc.z = fmaf(al, hv.z, acc.z);
    acc.w = fmaf(al, hv.w, acc.w);
  }
  float4 bb = ((const float4*)b1)[lane];
  acc.x = eluf(acc.x + bb.x);
  acc.y = eluf(acc.y + bb.y);
  acc.z = eluf(acc.z + bb.z);
  acc.w = eluf(acc.w + bb.w);
  ((float4*)hmid)[(size_t)n * 64 + lane] = acc;
}

// ---------------- GEMM2 + att2 fused: h2[N,40], a_src2/a_dst2[N] ----------------
// 256 rows/block, 256 threads, 8x5 register tile per thread. W2 staged once
// transposed (BT[col][k]) so B reads are ds_read_b128 covering 4 k-steps.
__global__ __launch_bounds__(256) void gemm2_kernel(const float* __restrict__ hmid,
                                                    const float* __restrict__ W2,
                                                    const float* __restrict__ as2,
                                                    const float* __restrict__ ad2,
                                                    float* __restrict__ h2,
                                                    float* __restrict__ a_src2,
                                                    float* __restrict__ a_dst2, int N) {
  __shared__ __align__(16) float BT[40][260];   // W2^T, [col][k]
  __shared__ __align__(16) float As[16][260];   // A k-slice, [k][row]
  __shared__ float asv[40], adv[40];
  int tid = threadIdx.x;
  for (int i = tid; i < 256 * 40; i += 256) {
    int k = i / 40, c = i - k * 40;
    BT[c][k] = W2[i];
  }
  if (tid < 40) { asv[tid] = as2[tid]; adv[tid] = ad2[tid]; }

  int row0 = blockIdx.x * 256;
  int myrow = row0 + tid;
  bool rowok = myrow < N;
  int tx = tid & 7, ty = tid >> 3;   // tx: col group (5 cols), ty: row group (8 rows)

  float acc[8][5];
#pragma unroll
  for (int i = 0; i < 8; ++i)
#pragma unroll
    for (int j = 0; j < 5; ++j) acc[i][j] = 0.f;

  for (int kc = 0; kc < 256; kc += 16) {
    __syncthreads();   // previous slice fully consumed (also covers BT/asv staging)
    float4 v[4];
#pragma unroll
    for (int q = 0; q < 4; ++q) v[q] = make_float4(0.f, 0.f, 0.f, 0.f);
    if (rowok) {
      const float4* src = (const float4*)(hmid + (size_t)myrow * 256 + kc);
#pragma unroll
      for (int q = 0; q < 4; ++q) v[q] = src[q];
    }
#pragma unroll
    for (int q = 0; q < 4; ++q) {
      As[q * 4 + 0][tid] = v[q].x;
      As[q * 4 + 1][tid] = v[q].y;
      As[q * 4 + 2][tid] = v[q].z;
      As[q * 4 + 3][tid] = v[q].w;
    }
    __syncthreads();
#pragma unroll
    for (int k4 = 0; k4 < 16; k4 += 4) {
      float4 aA[4], aB[4], b[5];
#pragma unroll
      for (int u = 0; u < 4; ++u) {
        aA[u] = *(const float4*)&As[k4 + u][ty * 8];
        aB[u] = *(const float4*)&As[k4 + u][ty * 8 + 4];
      }
#pragma unroll
      for (int j = 0; j < 5; ++j) b[j] = *(const float4*)&BT[tx * 5 + j][kc + k4];
#pragma unroll
      for (int u = 0; u < 4; ++u) {
        float av[8] = {aA[u].x, aA[u].y, aA[u].z, aA[u].w,
                       aB[u].x, aB[u].y, aB[u].z, aB[u].w};
        float bv[5] = {((const float*)&b[0])[u], ((const float*)&b[1])[u],
                       ((const float*)&b[2])[u], ((const float*)&b[3])[u],
                       ((const float*)&b[4])[u]};
#pragma unroll
        for (int i = 0; i < 8; ++i)
#pragma unroll
          for (int j = 0; j < 5; ++j) acc[i][j] = fmaf(av[i], bv[j], acc[i][j]);
      }
    }
  }

#pragma unroll
  for (int i = 0; i < 8; ++i) {
    int r = ty * 8 + i;
    int grow = row0 + r;
    float vs = 0.f, vd = 0.f;
#pragma unroll
    for (int j = 0; j < 5; ++j) {
      vs = fmaf(acc[i][j], asv[tx * 5 + j], vs);
      vd = fmaf(acc[i][j], adv[tx * 5 + j], vd);
    }
#pragma unroll
    for (int off = 1; off < 8; off <<= 1) {
      vs += __shfl_xor(vs, off);
      vd += __shfl_xor(vd, off);
    }
    if (grow < N) {
#pragma unroll
      for (int j = 0; j < 5; ++j) h2[(size_t)grow * 40 + tx * 5 + j] = acc[i][j];
      if (tx == 0) { a_src2[grow] = vs; a_dst2[grow] = vd; }
    }
  }
}

// ---------------- agg2: wave per node, 1 head x 40 ch ----------------
__global__ __launch_bounds__(256) void agg2_kernel(const float* __restrict__ h2,
                                                   const float* __restrict__ a_src,
                                                   const float* __restrict__ a_dst,
                                                   const int* __restrict__ row_ptr,
                                                   const int* __restrict__ col,
                                                   const float* __restrict__ b2,
                                                   float* __restrict__ out, int N) {
  int lane = threadIdx.x & 63;
  int n = blockIdx.x * 4 + (threadIdx.x >> 6);
  if (n >= N) return;
  int beg = row_ptr[n], deg = row_ptr[n + 1] - beg;
  float adst = a_dst[n];
  float mx = -1e30f;
  for (int e0 = 0; e0 < deg; e0 += 64) {
    int e = e0 + lane;
    if (e < deg) mx = fmaxf(mx, lrelu(a_src[col[beg + e]] + adst));
  }
#pragma unroll
  for (int off = 1; off < 64; off <<= 1) mx = fmaxf(mx, __shfl_xor(mx, off));
  float sum = 0.f;
  for (int e0 = 0; e0 < deg; e0 += 64) {
    int e = e0 + lane;
    if (e < deg) sum += __expf(lrelu(a_src[col[beg + e]] + adst) - mx);
  }
#pragma unroll
  for (int off = 1; off < 64; off <<= 1) sum += __shfl_xor(sum, off);
  float invden = 1.f / (sum + 1e-16f);
  float acc = 0.f;
  for (int e = 0; e < deg; ++e) {
    int s = col[beg + e];
    float al = __expf(lrelu(a_src[s] + adst) - mx) * invden;
    if (lane < 40) acc = fmaf(al, h2[(size_t)s * 40 + lane], acc);
  }
  if (lane < 40) out[(size_t)n * 40 + lane] = acc + b2[lane];
}

extern "C" void kernel_launch(void* const* d_in, const int* in_sizes, int n_in,
                              void* d_out, int out_size, void* d_ws, size_t ws_size,
                              hipStream_t stream) {
  const float* x   = (const float*)d_in[0];
  const int*   ei  = (const int*)d_in[1];
  const float* W1  = (const float*)d_in[2];
  const float* as1 = (const float*)d_in[3];
  const float* ad1 = (const float*)d_in[4];
  const float* b1  = (const float*)d_in[5];
  const float* W2  = (const float*)d_in[6];
  const float* as2 = (const float*)d_in[7];
  const float* ad2 = (const float*)d_in[8];
  const float* b2  = (const float*)d_in[9];
  float* out = (float*)d_out;

  int N = in_sizes[0] / 256;
  int E = in_sizes[1] / 2;
  int Etot = E + N;

  char* p = (char*)d_ws;
  auto alloc = [&](size_t bytes) -> char* {
    char* r = p;
    p += (bytes + 255) & ~(size_t)255;
    return r;
  };
  float* h1     = (float*)alloc((size_t)N * 256 * 4);
  float* hmid   = (float*)alloc((size_t)N * 256 * 4);
  float* a_src1 = (float*)alloc((size_t)N * 8 * 4);
  float* a_dst1 = (float*)alloc((size_t)N * 8 * 4);
  float* h2     = (float*)alloc((size_t)N * 40 * 4);
  float* a_src2 = (float*)alloc((size_t)N * 4);
  float* a_dst2 = (float*)alloc((size_t)N * 4);
  int* cnt      = (int*)alloc((size_t)N * 4);
  int* cursor   = (int*)alloc((size_t)N * 4);
  int* row_ptr  = (int*)alloc(((size_t)N + 1) * 4);
  int* tmp      = (int*)alloc((size_t)N * 4);
  int* bsum     = (int*)alloc(512);
  int* boff     = (int*)alloc(512);
  int* colx     = (int*)alloc((size_t)Etot * 4);

  hipMemsetAsync(cnt, 0, (size_t)N * 4, stream);

  int nbE = (Etot + 255) / 256;
  int nb1 = (N + 1023) / 1024;
  count_kernel<<<nbE, 256, 0, stream>>>(ei, cnt, E, N);
  scan1_kernel<<<nb1, 256, 0, stream>>>(cnt, tmp, bsum, N);
  scan2_kernel<<<1, 128, 0, stream>>>(bsum, boff, nb1);
  scan3_kernel<<<(N + 255) / 256, 256, 0, stream>>>(tmp, boff, row_ptr, cursor, N, Etot);
  fill_kernel<<<nbE, 256, 0, stream>>>(ei, cursor, colx, E, N);

  gemm1_kernel<<<(N + 63) / 64, 256, 0, stream>>>(x, W1, h1, N);
  att1_kernel<<<(N * 8 + 255) / 256, 256, 0, stream>>>(h1, as1, ad1, a_src1, a_dst1, N);
  agg1_kernel<<<(N + 3) / 4, 256, 0, stream>>>(h1, a_src1, a_dst1, row_ptr, colx, b1, hmid, N);
  gemm2_kernel<<<(N + 255) / 256, 256, 0, stream>>>(hmid, W2, as2, ad2, h2, a_src2, a_dst2, N);
  agg2_kernel<<<(N + 3) / 4, 256, 0, stream>>>(h2, a_src2, a_dst2, row_ptr, colx, b2, out, N);
}

// Round 3
// 623.510 us; speedup vs baseline: 1.3990x; 1.1907x over previous
//
#include <hip/hip_runtime.h>
#include <math.h>

#define NSLOPE 0.2f

__device__ __forceinline__ float lrelu(float x){ return x > 0.f ? x : NSLOPE * x; }
__device__ __forceinline__ float eluf(float x){ return x > 0.f ? x : expm1f(x); }

__device__ __forceinline__ unsigned short f2bf(float f) {
  unsigned u = __float_as_uint(f);
  u = (u + 0x7fff + ((u >> 16) & 1)) >> 16;   // RNE
  return (unsigned short)u;
}
__device__ __forceinline__ float bf2f(unsigned short h) {
  return __uint_as_float(((unsigned)h) << 16);
}

typedef __attribute__((ext_vector_type(8))) short bf16x8;
typedef __attribute__((ext_vector_type(4))) float f32x4;

// ---------------- conversions ----------------
__global__ __launch_bounds__(256) void conv_x_kernel(const float* __restrict__ x,
                                                     unsigned short* __restrict__ xb,
                                                     int total4) {
  int i = blockIdx.x * 256 + threadIdx.x;
  if (i >= total4) return;
  float4 v = ((const float4*)x)[i];
  ushort4 o;
  o.x = f2bf(v.x); o.y = f2bf(v.y); o.z = f2bf(v.z); o.w = f2bf(v.w);
  ((ushort4*)xb)[i] = o;
}

// W1[k][n] fp32 -> w1t[n][k] bf16 (256x256)
__global__ __launch_bounds__(256) void conv_w_kernel(const float* __restrict__ W,
                                                     unsigned short* __restrict__ wt) {
  int n = blockIdx.x;      // 0..255
  int k = threadIdx.x;     // 0..255
  wt[n * 256 + k] = f2bf(W[k * 256 + n]);
}

// ---------------- GEMM1 (MFMA): h1b[N,256] = xb[N,256] @ W1 ----------------
// 128x128 tile, 256 threads (4 waves), each wave 64x64 via 4x4 16x16x32 mfma.
__global__ __launch_bounds__(256) void gemm1_mfma_kernel(const unsigned short* __restrict__ xb,
                                                         const unsigned short* __restrict__ wt,
                                                         unsigned short* __restrict__ h1b,
                                                         int N) {
  __shared__ __align__(16) unsigned short Asl[128][40];  // [m][k], pitch 80B
  __shared__ __align__(16) unsigned short Bsl[128][40];  // [n][k]
  int tid = threadIdx.x;
  int bm = blockIdx.x >> 1, bn = blockIdx.x & 1;
  int row0 = bm * 128, col0 = bn * 128;

  int lr = tid >> 2;             // 0..63
  int lk = (tid & 3) * 8;        // k offset in bf16

  int lane = tid & 63, wv = tid >> 6;
  int m0 = (wv & 1) * 64, n0 = (wv >> 1) * 64;
  int lm = lane & 15, quad = lane >> 4;

  f32x4 acc[4][4];
#pragma unroll
  for (int i = 0; i < 4; ++i)
#pragma unroll
    for (int j = 0; j < 4; ++j) acc[i][j] = (f32x4){0.f, 0.f, 0.f, 0.f};

  for (int kc = 0; kc < 256; kc += 32) {
    uint4 av0 = {0,0,0,0}, av1 = {0,0,0,0};
    int r0 = row0 + lr, r1 = row0 + 64 + lr;
    if (r0 < N) av0 = *(const uint4*)(xb + (size_t)r0 * 256 + kc + lk);
    if (r1 < N) av1 = *(const uint4*)(xb + (size_t)r1 * 256 + kc + lk);
    uint4 bv0 = *(const uint4*)(wt + (size_t)(col0 + lr) * 256 + kc + lk);
    uint4 bv1 = *(const uint4*)(wt + (size_t)(col0 + 64 + lr) * 256 + kc + lk);
    __syncthreads();   // previous compute done before overwrite
    *(uint4*)&Asl[lr][lk]      = av0;
    *(uint4*)&Asl[64 + lr][lk] = av1;
    *(uint4*)&Bsl[lr][lk]      = bv0;
    *(uint4*)&Bsl[64 + lr][lk] = bv1;
    __syncthreads();
    bf16x8 aF[4], bF[4];
#pragma unroll
    for (int i = 0; i < 4; ++i) aF[i] = *(const bf16x8*)&Asl[m0 + i * 16 + lm][quad * 8];
#pragma unroll
    for (int j = 0; j < 4; ++j) bF[j] = *(const bf16x8*)&Bsl[n0 + j * 16 + lm][quad * 8];
#pragma unroll
    for (int i = 0; i < 4; ++i)
#pragma unroll
      for (int j = 0; j < 4; ++j)
        acc[i][j] = __builtin_amdgcn_mfma_f32_16x16x32_bf16(aF[i], bF[j], acc[i][j], 0, 0, 0);
  }

#pragma unroll
  for (int i = 0; i < 4; ++i) {
#pragma unroll
    for (int j = 0; j < 4; ++j) {
      int gc = col0 + n0 + j * 16 + lm;
      int grb = row0 + m0 + i * 16 + quad * 4;
#pragma unroll
      for (int r = 0; r < 4; ++r) {
        int grow = grb + r;
        if (grow < N) h1b[(size_t)grow * 256 + gc] = f2bf(acc[i][j][r]);
      }
    }
  }
}

// ---------------- att1: a_src/a_dst [N,8] from bf16 h1 ----------------
__global__ __launch_bounds__(256) void att1_kernel(const unsigned short* __restrict__ h1b,
                                                   const float* __restrict__ att_src,
                                                   const float* __restrict__ att_dst,
                                                   float* __restrict__ a_src,
                                                   float* __restrict__ a_dst, int N) {
  __shared__ float sas[256];
  __shared__ float sad[256];
  int tid = threadIdx.x;
  sas[tid] = att_src[tid];
  sad[tid] = att_dst[tid];
  __syncthreads();
  int gid = blockIdx.x * 256 + tid;
  if (gid >= N * 8) return;
  int h = gid & 7;
  const uint4* hv = (const uint4*)(h1b + (size_t)(gid >> 3) * 256 + h * 32);
  float s1 = 0.f, s2 = 0.f;
#pragma unroll
  for (int q = 0; q < 4; ++q) {
    uint4 u = hv[q];
    unsigned uu[4] = {u.x, u.y, u.z, u.w};
#pragma unroll
    for (int e = 0; e < 4; ++e) {
      float lo = bf2f((unsigned short)(uu[e] & 0xffff));
      float hi = bf2f((unsigned short)(uu[e] >> 16));
      int c = h * 32 + q * 8 + e * 2;
      s1 += lo * sas[c] + hi * sas[c + 1];
      s2 += lo * sad[c] + hi * sad[c + 1];
    }
  }
  a_src[gid] = s1;
  a_dst[gid] = s2;
}

// ---------------- CSR build ----------------
__global__ void count_kernel(const int* __restrict__ ei, int* __restrict__ cnt, int E, int N) {
  int e = blockIdx.x * 256 + threadIdx.x;
  if (e >= E + N) return;
  int d = (e < E) ? ei[E + e] : (e - E);
  atomicAdd(&cnt[d], 1);
}

__global__ __launch_bounds__(256) void scan1_kernel(const int* __restrict__ cnt,
                                                    int* __restrict__ tmp,
                                                    int* __restrict__ bsum, int N) {
  __shared__ int sh[256];
  int t = threadIdx.x;
  int base = blockIdx.x * 1024 + t * 4;
  int v[4]; int s = 0;
#pragma unroll
  for (int j = 0; j < 4; ++j) { v[j] = (base + j < N) ? cnt[base + j] : 0; s += v[j]; }
  sh[t] = s;
  __syncthreads();
  for (int off = 1; off < 256; off <<= 1) {
    int xv = (t >= off) ? sh[t - off] : 0;
    __syncthreads();
    sh[t] += xv;
    __syncthreads();
  }
  if (t == 255) bsum[blockIdx.x] = sh[255];
  int run = sh[t] - s;  // exclusive
#pragma unroll
  for (int j = 0; j < 4; ++j) {
    if (base + j < N) tmp[base + j] = run;
    run += v[j];
  }
}

__global__ __launch_bounds__(128) void scan2_kernel(const int* __restrict__ bsum,
                                                    int* __restrict__ boff, int nb) {
  __shared__ int sh[128];
  int t = threadIdx.x;
  int v = (t < nb) ? bsum[t] : 0;
  sh[t] = v;
  __syncthreads();
  for (int off = 1; off < 128; off <<= 1) {
    int xv = (t >= off) ? sh[t - off] : 0;
    __syncthreads();
    sh[t] += xv;
    __syncthreads();
  }
  if (t < nb) boff[t] = sh[t] - v;
}

__global__ void scan3_kernel(const int* __restrict__ tmp, const int* __restrict__ boff,
                             int* __restrict__ row_ptr, int* __restrict__ cursor,
                             int N, int Etot) {
  int i = blockIdx.x * 256 + threadIdx.x;
  if (i == 0) row_ptr[N] = Etot;
  if (i >= N) return;
  int rp = tmp[i] + boff[i >> 10];
  row_ptr[i] = rp;
  cursor[i] = rp;
}

__global__ void fill_kernel(const int* __restrict__ ei, int* __restrict__ cursor,
                            int* __restrict__ col, int E, int N) {
  int e = blockIdx.x * 256 + threadIdx.x;
  if (e >= E + N) return;
  int s, d;
  if (e < E) { s = ei[e]; d = ei[E + e]; } else { s = e - E; d = s; }
  int pos = atomicAdd(&cursor[d], 1);
  col[pos] = s;
}

// ---------------- agg1: wave per node, bf16 h1 gather ----------------
__global__ __launch_bounds__(256) void agg1_kernel(const unsigned short* __restrict__ h1b,
                                                   const float* __restrict__ a_src,
                                                   const float* __restrict__ a_dst,
                                                   const int* __restrict__ row_ptr,
                                                   const int* __restrict__ col,
                                                   const float* __restrict__ b1,
                                                   float* __restrict__ hmid, int N) {
  int lane = threadIdx.x & 63;
  int n = blockIdx.x * 4 + (threadIdx.x >> 6);
  if (n >= N) return;
  int beg = row_ptr[n], deg = row_ptr[n + 1] - beg;

  int hA = lane & 7, eoA = lane >> 3;
  float adst = a_dst[n * 8 + hA];
  float mx = -1e30f;
  for (int e0 = 0; e0 < deg; e0 += 8) {
    int e = e0 + eoA;
    if (e < deg) {
      int s = col[beg + e];
      mx = fmaxf(mx, lrelu(a_src[s * 8 + hA] + adst));
    }
  }
#pragma unroll
  for (int off = 8; off < 64; off <<= 1) mx = fmaxf(mx, __shfl_xor(mx, off));
  float sum = 0.f;
  for (int e0 = 0; e0 < deg; e0 += 8) {
    int e = e0 + eoA;
    if (e < deg) {
      int s = col[beg + e];
      sum += __expf(lrelu(a_src[s * 8 + hA] + adst) - mx);
    }
  }
#pragma unroll
  for (int off = 8; off < 64; off <<= 1) sum += __shfl_xor(sum, off);
  float invden = 1.f / (sum + 1e-16f);

  int hB = lane >> 3;                 // head owning channels lane*4..lane*4+3
  float mB   = __shfl(mx, hB);
  float invB = __shfl(invden, hB);
  float adB  = __shfl(adst, hB);

  float4 acc = make_float4(0.f, 0.f, 0.f, 0.f);
  for (int e = 0; e < deg; ++e) {
    int s = col[beg + e];
    float v = lrelu(a_src[s * 8 + hB] + adB);
    float al = __expf(v - mB) * invB;
    ushort4 hv = *(const ushort4*)(h1b + (size_t)s * 256 + lane * 4);
    acc.x = fmaf(al, bf2f(hv.x), acc.x);
    acc.y = fmaf(al, bf2f(hv.y), acc.y);
    acc.z = fmaf(al, bf2f(hv.z), acc.z);
    acc.w = fmaf(al, bf2f(hv.w), acc.w);
  }
  float4 bb = ((const float4*)b1)[lane];
  acc.x = eluf(acc.x + bb.x);
  acc.y = eluf(acc.y + bb.y);
  acc.z = eluf(acc.z + bb.z);
  acc.w = eluf(acc.w + bb.w);
  ((float4*)hmid)[(size_t)n * 64 + lane] = acc;
}

// ---------------- GEMM2 + att2 fused: h2[N,40], a_src2/a_dst2[N] ----------------
__global__ __launch_bounds__(256) void gemm2_kernel(const float* __restrict__ hmid,
                                                    const float* __restrict__ W2,
                                                    const float* __restrict__ as2,
                                                    const float* __restrict__ ad2,
                                                    float* __restrict__ h2,
                                                    float* __restrict__ a_src2,
                                                    float* __restrict__ a_dst2, int N) {
  __shared__ __align__(16) float BT[40][260];   // W2^T, [col][k]
  __shared__ __align__(16) float As[16][260];   // A k-slice, [k][row]
  __shared__ float asv[40], adv[40];
  int tid = threadIdx.x;
  for (int i = tid; i < 256 * 40; i += 256) {
    int k = i / 40, c = i - k * 40;
    BT[c][k] = W2[i];
  }
  if (tid < 40) { asv[tid] = as2[tid]; adv[tid] = ad2[tid]; }

  int row0 = blockIdx.x * 256;
  int myrow = row0 + tid;
  bool rowok = myrow < N;
  int tx = tid & 7, ty = tid >> 3;   // tx: col group (5 cols), ty: row group (8 rows)

  float acc[8][5];
#pragma unroll
  for (int i = 0; i < 8; ++i)
#pragma unroll
    for (int j = 0; j < 5; ++j) acc[i][j] = 0.f;

  for (int kc = 0; kc < 256; kc += 16) {
    __syncthreads();   // previous slice fully consumed (also covers BT/asv staging)
    float4 v[4];
#pragma unroll
    for (int q = 0; q < 4; ++q) v[q] = make_float4(0.f, 0.f, 0.f, 0.f);
    if (rowok) {
      const float4* src = (const float4*)(hmid + (size_t)myrow * 256 + kc);
#pragma unroll
      for (int q = 0; q < 4; ++q) v[q] = src[q];
    }
#pragma unroll
    for (int q = 0; q < 4; ++q) {
      As[q * 4 + 0][tid] = v[q].x;
      As[q * 4 + 1][tid] = v[q].y;
      As[q * 4 + 2][tid] = v[q].z;
      As[q * 4 + 3][tid] = v[q].w;
    }
    __syncthreads();
#pragma unroll
    for (int k4 = 0; k4 < 16; k4 += 4) {
      float4 aA[4], aB[4], b[5];
#pragma unroll
      for (int u = 0; u < 4; ++u) {
        aA[u] = *(const float4*)&As[k4 + u][ty * 8];
        aB[u] = *(const float4*)&As[k4 + u][ty * 8 + 4];
      }
#pragma unroll
      for (int j = 0; j < 5; ++j) b[j] = *(const float4*)&BT[tx * 5 + j][kc + k4];
#pragma unroll
      for (int u = 0; u < 4; ++u) {
        float av[8] = {aA[u].x, aA[u].y, aA[u].z, aA[u].w,
                       aB[u].x, aB[u].y, aB[u].z, aB[u].w};
        float bv[5] = {((const float*)&b[0])[u], ((const float*)&b[1])[u],
                       ((const float*)&b[2])[u], ((const float*)&b[3])[u],
                       ((const float*)&b[4])[u]};
#pragma unroll
        for (int i = 0; i < 8; ++i)
#pragma unroll
          for (int j = 0; j < 5; ++j) acc[i][j] = fmaf(av[i], bv[j], acc[i][j]);
      }
    }
  }

#pragma unroll
  for (int i = 0; i < 8; ++i) {
    int r = ty * 8 + i;
    int grow = row0 + r;
    float vs = 0.f, vd = 0.f;
#pragma unroll
    for (int j = 0; j < 5; ++j) {
      vs = fmaf(acc[i][j], asv[tx * 5 + j], vs);
      vd = fmaf(acc[i][j], adv[tx * 5 + j], vd);
    }
#pragma unroll
    for (int off = 1; off < 8; off <<= 1) {
      vs += __shfl_xor(vs, off);
      vd += __shfl_xor(vd, off);
    }
    if (grow < N) {
#pragma unroll
      for (int j = 0; j < 5; ++j) h2[(size_t)grow * 40 + tx * 5 + j] = acc[i][j];
      if (tx == 0) { a_src2[grow] = vs; a_dst2[grow] = vd; }
    }
  }
}

// ---------------- agg2: wave per node, 1 head x 40 ch ----------------
__global__ __launch_bounds__(256) void agg2_kernel(const float* __restrict__ h2,
                                                   const float* __restrict__ a_src,
                                                   const float* __restrict__ a_dst,
                                                   const int* __restrict__ row_ptr,
                                                   const int* __restrict__ col,
                                                   const float* __restrict__ b2,
                                                   float* __restrict__ out, int N) {
  int lane = threadIdx.x & 63;
  int n = blockIdx.x * 4 + (threadIdx.x >> 6);
  if (n >= N) return;
  int beg = row_ptr[n], deg = row_ptr[n + 1] - beg;
  float adst = a_dst[n];
  float mx = -1e30f;
  for (int e0 = 0; e0 < deg; e0 += 64) {
    int e = e0 + lane;
    if (e < deg) mx = fmaxf(mx, lrelu(a_src[col[beg + e]] + adst));
  }
#pragma unroll
  for (int off = 1; off < 64; off <<= 1) mx = fmaxf(mx, __shfl_xor(mx, off));
  float sum = 0.f;
  for (int e0 = 0; e0 < deg; e0 += 64) {
    int e = e0 + lane;
    if (e < deg) sum += __expf(lrelu(a_src[col[beg + e]] + adst) - mx);
  }
#pragma unroll
  for (int off = 1; off < 64; off <<= 1) sum += __shfl_xor(sum, off);
  float invden = 1.f / (sum + 1e-16f);
  float acc = 0.f;
  for (int e = 0; e < deg; ++e) {
    int s = col[beg + e];
    float al = __expf(lrelu(a_src[s] + adst) - mx) * invden;
    if (lane < 40) acc = fmaf(al, h2[(size_t)s * 40 + lane], acc);
  }
  if (lane < 40) out[(size_t)n * 40 + lane] = acc + b2[lane];
}

extern "C" void kernel_launch(void* const* d_in, const int* in_sizes, int n_in,
                              void* d_out, int out_size, void* d_ws, size_t ws_size,
                              hipStream_t stream) {
  const float* x   = (const float*)d_in[0];
  const int*   ei  = (const int*)d_in[1];
  const float* W1  = (const float*)d_in[2];
  const float* as1 = (const float*)d_in[3];
  const float* ad1 = (const float*)d_in[4];
  const float* b1  = (const float*)d_in[5];
  const float* W2  = (const float*)d_in[6];
  const float* as2 = (const float*)d_in[7];
  const float* ad2 = (const float*)d_in[8];
  const float* b2  = (const float*)d_in[9];
  float* out = (float*)d_out;

  int N = in_sizes[0] / 256;
  int E = in_sizes[1] / 2;
  int Etot = E + N;

  char* p = (char*)d_ws;
  auto alloc = [&](size_t bytes) -> char* {
    char* r = p;
    p += (bytes + 255) & ~(size_t)255;
    return r;
  };
  unsigned short* xb  = (unsigned short*)alloc((size_t)N * 256 * 2);
  unsigned short* w1t = (unsigned short*)alloc((size_t)256 * 256 * 2);
  unsigned short* h1b = (unsigned short*)alloc((size_t)N * 256 * 2);
  float* hmid   = (float*)alloc((size_t)N * 256 * 4);
  float* a_src1 = (float*)alloc((size_t)N * 8 * 4);
  float* a_dst1 = (float*)alloc((size_t)N * 8 * 4);
  float* h2     = (float*)alloc((size_t)N * 40 * 4);
  float* a_src2 = (float*)alloc((size_t)N * 4);
  float* a_dst2 = (float*)alloc((size_t)N * 4);
  int* cnt      = (int*)alloc((size_t)N * 4);
  int* cursor   = (int*)alloc((size_t)N * 4);
  int* row_ptr  = (int*)alloc(((size_t)N + 1) * 4);
  int* tmp      = (int*)alloc((size_t)N * 4);
  int* bsum     = (int*)alloc(512);
  int* boff     = (int*)alloc(512);
  int* colx     = (int*)alloc((size_t)Etot * 4);

  hipMemsetAsync(cnt, 0, (size_t)N * 4, stream);

  int nbE = (Etot + 255) / 256;
  int nb1 = (N + 1023) / 1024;
  count_kernel<<<nbE, 256, 0, stream>>>(ei, cnt, E, N);
  scan1_kernel<<<nb1, 256, 0, stream>>>(cnt, tmp, bsum, N);
  scan2_kernel<<<1, 128, 0, stream>>>(bsum, boff, nb1);
  scan3_kernel<<<(N + 255) / 256, 256, 0, stream>>>(tmp, boff, row_ptr, cursor, N, Etot);
  fill_kernel<<<nbE, 256, 0, stream>>>(ei, cursor, colx, E, N);

  conv_x_kernel<<<(N * 64 + 255) / 256, 256, 0, stream>>>(x, xb, N * 64);
  conv_w_kernel<<<256, 256, 0, stream>>>(W1, w1t);
  gemm1_mfma_kernel<<<((N + 127) / 128) * 2, 256, 0, stream>>>(xb, w1t, h1b, N);
  att1_kernel<<<(N * 8 + 255) / 256, 256, 0, stream>>>(h1b, as1, ad1, a_src1, a_dst1, N);
  agg1_kernel<<<(N + 3) / 4, 256, 0, stream>>>(h1b, a_src1, a_dst1, row_ptr, colx, b1, hmid, N);
  gemm2_kernel<<<(N + 255) / 256, 256, 0, stream>>>(hmid, W2, as2, ad2, h2, a_src2, a_dst2, N);
  agg2_kernel<<<(N + 3) / 4, 256, 0, stream>>>(h2, a_src2, a_dst2, row_ptr, colx, b2, out, N);
}

// Round 4
// 566.769 us; speedup vs baseline: 1.5390x; 1.1001x over previous
//
#include <hip/hip_runtime.h>
#include <math.h>

#define NSLOPE 0.2f

__device__ __forceinline__ float lrelu(float x){ return x > 0.f ? x : NSLOPE * x; }
__device__ __forceinline__ float eluf(float x){ return x > 0.f ? x : expm1f(x); }

__device__ __forceinline__ unsigned short f2bf(float f) {
  unsigned u = __float_as_uint(f);
  u = (u + 0x7fff + ((u >> 16) & 1)) >> 16;   // RNE
  return (unsigned short)u;
}
__device__ __forceinline__ float bf2f(unsigned short h) {
  return __uint_as_float(((unsigned)h) << 16);
}

typedef __attribute__((ext_vector_type(8))) short bf16x8;
typedef __attribute__((ext_vector_type(4))) float f32x4;

// ---------------- conversions ----------------
__global__ __launch_bounds__(256) void conv_x_kernel(const float* __restrict__ x,
                                                     unsigned short* __restrict__ xb,
                                                     int total4) {
  int i = blockIdx.x * 256 + threadIdx.x;
  if (i >= total4) return;
  float4 v = ((const float4*)x)[i];
  ushort4 o;
  o.x = f2bf(v.x); o.y = f2bf(v.y); o.z = f2bf(v.z); o.w = f2bf(v.w);
  ((ushort4*)xb)[i] = o;
}

// W1[k][n] fp32 -> w1t[n][k] bf16 (256x256)
__global__ __launch_bounds__(256) void conv_w_kernel(const float* __restrict__ W,
                                                     unsigned short* __restrict__ wt) {
  int n = blockIdx.x;      // 0..255
  int k = threadIdx.x;     // 0..255
  wt[n * 256 + k] = f2bf(W[k * 256 + n]);
}

// ---------------- GEMM1 (MFMA): h1b[N,256] = xb[N,256] @ W1 ----------------
__global__ __launch_bounds__(256) void gemm1_mfma_kernel(const unsigned short* __restrict__ xb,
                                                         const unsigned short* __restrict__ wt,
                                                         unsigned short* __restrict__ h1b,
                                                         int N) {
  __shared__ __align__(16) unsigned short Asl[128][40];  // [m][k], pitch 80B
  __shared__ __align__(16) unsigned short Bsl[128][40];  // [n][k]
  int tid = threadIdx.x;
  int bm = blockIdx.x >> 1, bn = blockIdx.x & 1;
  int row0 = bm * 128, col0 = bn * 128;

  int lr = tid >> 2;             // 0..63
  int lk = (tid & 3) * 8;        // k offset in bf16

  int lane = tid & 63, wv = tid >> 6;
  int m0 = (wv & 1) * 64, n0 = (wv >> 1) * 64;
  int lm = lane & 15, quad = lane >> 4;

  f32x4 acc[4][4];
#pragma unroll
  for (int i = 0; i < 4; ++i)
#pragma unroll
    for (int j = 0; j < 4; ++j) acc[i][j] = (f32x4){0.f, 0.f, 0.f, 0.f};

  for (int kc = 0; kc < 256; kc += 32) {
    uint4 av0 = {0,0,0,0}, av1 = {0,0,0,0};
    int r0 = row0 + lr, r1 = row0 + 64 + lr;
    if (r0 < N) av0 = *(const uint4*)(xb + (size_t)r0 * 256 + kc + lk);
    if (r1 < N) av1 = *(const uint4*)(xb + (size_t)r1 * 256 + kc + lk);
    uint4 bv0 = *(const uint4*)(wt + (size_t)(col0 + lr) * 256 + kc + lk);
    uint4 bv1 = *(const uint4*)(wt + (size_t)(col0 + 64 + lr) * 256 + kc + lk);
    __syncthreads();
    *(uint4*)&Asl[lr][lk]      = av0;
    *(uint4*)&Asl[64 + lr][lk] = av1;
    *(uint4*)&Bsl[lr][lk]      = bv0;
    *(uint4*)&Bsl[64 + lr][lk] = bv1;
    __syncthreads();
    bf16x8 aF[4], bF[4];
#pragma unroll
    for (int i = 0; i < 4; ++i) aF[i] = *(const bf16x8*)&Asl[m0 + i * 16 + lm][quad * 8];
#pragma unroll
    for (int j = 0; j < 4; ++j) bF[j] = *(const bf16x8*)&Bsl[n0 + j * 16 + lm][quad * 8];
#pragma unroll
    for (int i = 0; i < 4; ++i)
#pragma unroll
      for (int j = 0; j < 4; ++j)
        acc[i][j] = __builtin_amdgcn_mfma_f32_16x16x32_bf16(aF[i], bF[j], acc[i][j], 0, 0, 0);
  }

#pragma unroll
  for (int i = 0; i < 4; ++i) {
#pragma unroll
    for (int j = 0; j < 4; ++j) {
      int gc = col0 + n0 + j * 16 + lm;
      int grb = row0 + m0 + i * 16 + quad * 4;
#pragma unroll
      for (int r = 0; r < 4; ++r) {
        int grow = grb + r;
        if (grow < N) h1b[(size_t)grow * 256 + gc] = f2bf(acc[i][j][r]);
      }
    }
  }
}

// ---------------- att1: a_src/a_dst [N,8] from bf16 h1 ----------------
__global__ __launch_bounds__(256) void att1_kernel(const unsigned short* __restrict__ h1b,
                                                   const float* __restrict__ att_src,
                                                   const float* __restrict__ att_dst,
                                                   float* __restrict__ a_src,
                                                   float* __restrict__ a_dst, int N) {
  __shared__ float sas[256];
  __shared__ float sad[256];
  int tid = threadIdx.x;
  sas[tid] = att_src[tid];
  sad[tid] = att_dst[tid];
  __syncthreads();
  int gid = blockIdx.x * 256 + tid;
  if (gid >= N * 8) return;
  int h = gid & 7;
  const uint4* hv = (const uint4*)(h1b + (size_t)(gid >> 3) * 256 + h * 32);
  float s1 = 0.f, s2 = 0.f;
#pragma unroll
  for (int q = 0; q < 4; ++q) {
    uint4 u = hv[q];
    unsigned uu[4] = {u.x, u.y, u.z, u.w};
#pragma unroll
    for (int e = 0; e < 4; ++e) {
      float lo = __uint_as_float(uu[e] << 16);
      float hi = __uint_as_float(uu[e] & 0xffff0000u);
      int c = h * 32 + q * 8 + e * 2;
      s1 += lo * sas[c] + hi * sas[c + 1];
      s2 += lo * sad[c] + hi * sad[c + 1];
    }
  }
  a_src[gid] = s1;
  a_dst[gid] = s2;
}

// ---------------- CSR build ----------------
__global__ void count_kernel(const int* __restrict__ ei, int* __restrict__ cnt, int E, int N) {
  int e = blockIdx.x * 256 + threadIdx.x;
  if (e >= E + N) return;
  int d = (e < E) ? ei[E + e] : (e - E);
  atomicAdd(&cnt[d], 1);
}

__global__ __launch_bounds__(256) void scan1_kernel(const int* __restrict__ cnt,
                                                    int* __restrict__ tmp,
                                                    int* __restrict__ bsum, int N) {
  __shared__ int sh[256];
  int t = threadIdx.x;
  int base = blockIdx.x * 1024 + t * 4;
  int v[4]; int s = 0;
#pragma unroll
  for (int j = 0; j < 4; ++j) { v[j] = (base + j < N) ? cnt[base + j] : 0; s += v[j]; }
  sh[t] = s;
  __syncthreads();
  for (int off = 1; off < 256; off <<= 1) {
    int xv = (t >= off) ? sh[t - off] : 0;
    __syncthreads();
    sh[t] += xv;
    __syncthreads();
  }
  if (t == 255) bsum[blockIdx.x] = sh[255];
  int run = sh[t] - s;  // exclusive
#pragma unroll
  for (int j = 0; j < 4; ++j) {
    if (base + j < N) tmp[base + j] = run;
    run += v[j];
  }
}

__global__ __launch_bounds__(128) void scan2_kernel(const int* __restrict__ bsum,
                                                    int* __restrict__ boff, int nb) {
  __shared__ int sh[128];
  int t = threadIdx.x;
  int v = (t < nb) ? bsum[t] : 0;
  sh[t] = v;
  __syncthreads();
  for (int off = 1; off < 128; off <<= 1) {
    int xv = (t >= off) ? sh[t - off] : 0;
    __syncthreads();
    sh[t] += xv;
    __syncthreads();
  }
  if (t < nb) boff[t] = sh[t] - v;
}

__global__ void scan3_kernel(const int* __restrict__ tmp, const int* __restrict__ boff,
                             int* __restrict__ row_ptr, int* __restrict__ cursor,
                             int N, int Etot) {
  int i = blockIdx.x * 256 + threadIdx.x;
  if (i == 0) row_ptr[N] = Etot;
  if (i >= N) return;
  int rp = tmp[i] + boff[i >> 10];
  row_ptr[i] = rp;
  cursor[i] = rp;
}

__global__ void fill_kernel(const int* __restrict__ ei, int* __restrict__ cursor,
                            int* __restrict__ col, int E, int N) {
  int e = blockIdx.x * 256 + threadIdx.x;
  if (e >= E + N) return;
  int s, d;
  if (e < E) { s = ei[e]; d = ei[E + e]; } else { s = e - E; d = s; }
  int pos = atomicAdd(&cursor[d], 1);
  col[pos] = s;
}

// ---------------- agg1: wave per node, batched alpha, half-wave-per-edge gather ----------------
__global__ __launch_bounds__(256) void agg1_kernel(const unsigned short* __restrict__ h1b,
                                                   const float* __restrict__ a_src,
                                                   const float* __restrict__ a_dst,
                                                   const int* __restrict__ row_ptr,
                                                   const int* __restrict__ col,
                                                   const float* __restrict__ b1,
                                                   unsigned short* __restrict__ hmidb, int N) {
  int lane = threadIdx.x & 63;
  int n = blockIdx.x * 4 + (threadIdx.x >> 6);
  if (n >= N) return;
  int beg = row_ptr[n], deg = row_ptr[n + 1] - beg;

  int hA = lane & 7, eoA = lane >> 3;
  float adst = a_dst[n * 8 + hA];
  float mx = -1e30f;
  for (int e0 = 0; e0 < deg; e0 += 8) {
    int e = e0 + eoA;
    if (e < deg) mx = fmaxf(mx, lrelu(a_src[col[beg + e] * 8 + hA] + adst));
  }
#pragma unroll
  for (int off = 8; off < 64; off <<= 1) mx = fmaxf(mx, __shfl_xor(mx, off));
  float sum = 0.f;
  for (int e0 = 0; e0 < deg; e0 += 8) {
    int e = e0 + eoA;
    if (e < deg) sum += __expf(lrelu(a_src[col[beg + e] * 8 + hA] + adst) - mx);
  }
#pragma unroll
  for (int off = 8; off < 64; off <<= 1) sum += __shfl_xor(sum, off);
  float invden = 1.f / (sum + 1e-16f);

  int half = lane >> 5;     // 0: even edges, 1: odd edges
  int cl = lane & 31;       // channel group: channels cl*8 .. cl*8+7
  int hB = cl >> 2;         // head for this channel group
  float4 acc0 = {0.f,0.f,0.f,0.f}, acc1 = {0.f,0.f,0.f,0.f};

  for (int c0 = 0; c0 < deg; c0 += 8) {
    // batch compute alpha for up to 8 edges x 8 heads across 64 lanes
    int eb = c0 + eoA;
    int ec = eb < deg ? eb : deg - 1;
    int sB = col[beg + ec];
    float alB = 0.f;
    if (eb < deg) alB = __expf(lrelu(a_src[sB * 8 + hA] + adst) - mx) * invden;
    int rem = deg - c0; if (rem > 8) rem = 8;
#pragma unroll
    for (int p = 0; p < 4; ++p) {
      int myE = 2 * p + half;
      int s = __shfl(sB, myE * 8);
      float al = __shfl(alB, myE * 8 + hB);
      if (myE < rem) {
        uint4 hv = *(const uint4*)(h1b + (size_t)s * 256 + cl * 8);
        acc0.x = fmaf(al, __uint_as_float(hv.x << 16), acc0.x);
        acc0.y = fmaf(al, __uint_as_float(hv.x & 0xffff0000u), acc0.y);
        acc0.z = fmaf(al, __uint_as_float(hv.y << 16), acc0.z);
        acc0.w = fmaf(al, __uint_as_float(hv.y & 0xffff0000u), acc0.w);
        acc1.x = fmaf(al, __uint_as_float(hv.z << 16), acc1.x);
        acc1.y = fmaf(al, __uint_as_float(hv.z & 0xffff0000u), acc1.y);
        acc1.z = fmaf(al, __uint_as_float(hv.w << 16), acc1.z);
        acc1.w = fmaf(al, __uint_as_float(hv.w & 0xffff0000u), acc1.w);
      }
    }
  }
  // combine halves: lanes 0-31 add partner lane+32's accumulators
  float po[8] = {acc0.x, acc0.y, acc0.z, acc0.w, acc1.x, acc1.y, acc1.z, acc1.w};
#pragma unroll
  for (int j = 0; j < 8; ++j) po[j] += __shfl(po[j], cl + 32);
  if (half == 0) {
    const float4* b4 = (const float4*)(b1 + cl * 8);
    float4 bb0 = b4[0], bb1 = b4[1];
    float r0 = eluf(po[0] + bb0.x), r1 = eluf(po[1] + bb0.y);
    float r2 = eluf(po[2] + bb0.z), r3 = eluf(po[3] + bb0.w);
    float r4 = eluf(po[4] + bb1.x), r5 = eluf(po[5] + bb1.y);
    float r6 = eluf(po[6] + bb1.z), r7 = eluf(po[7] + bb1.w);
    uint4 ov;
    ov.x = (unsigned)f2bf(r0) | ((unsigned)f2bf(r1) << 16);
    ov.y = (unsigned)f2bf(r2) | ((unsigned)f2bf(r3) << 16);
    ov.z = (unsigned)f2bf(r4) | ((unsigned)f2bf(r5) << 16);
    ov.w = (unsigned)f2bf(r6) | ((unsigned)f2bf(r7) << 16);
    *(uint4*)(hmidb + (size_t)n * 256 + cl * 8) = ov;
  }
}

// ---------------- GEMM2 + att2 fused: h2[N,40] = hmid(bf16) @ W2 ----------------
__global__ __launch_bounds__(256) void gemm2_kernel(const unsigned short* __restrict__ hmidb,
                                                    const float* __restrict__ W2,
                                                    const float* __restrict__ as2,
                                                    const float* __restrict__ ad2,
                                                    float* __restrict__ h2,
                                                    float* __restrict__ a_src2,
                                                    float* __restrict__ a_dst2, int N) {
  __shared__ __align__(16) float BT[40][260];   // W2^T, [col][k]
  __shared__ __align__(16) float As[16][260];   // A k-slice, [k][row]
  __shared__ float asv[40], adv[40];
  int tid = threadIdx.x;
  for (int i = tid; i < 256 * 40; i += 256) {
    int k = i / 40, c = i - k * 40;
    BT[c][k] = W2[i];
  }
  if (tid < 40) { asv[tid] = as2[tid]; adv[tid] = ad2[tid]; }

  int row0 = blockIdx.x * 256;
  int myrow = row0 + tid;
  bool rowok = myrow < N;
  int tx = tid & 7, ty = tid >> 3;

  float acc[8][5];
#pragma unroll
  for (int i = 0; i < 8; ++i)
#pragma unroll
    for (int j = 0; j < 5; ++j) acc[i][j] = 0.f;

  for (int kc = 0; kc < 256; kc += 16) {
    __syncthreads();
    uint4 u0 = {0,0,0,0}, u1 = {0,0,0,0};
    if (rowok) {
      const uint4* src = (const uint4*)(hmidb + (size_t)myrow * 256 + kc);
      u0 = src[0]; u1 = src[1];
    }
    unsigned uu[8] = {u0.x, u0.y, u0.z, u0.w, u1.x, u1.y, u1.z, u1.w};
#pragma unroll
    for (int q = 0; q < 8; ++q) {
      As[q * 2 + 0][tid] = __uint_as_float(uu[q] << 16);
      As[q * 2 + 1][tid] = __uint_as_float(uu[q] & 0xffff0000u);
    }
    __syncthreads();
#pragma unroll
    for (int k4 = 0; k4 < 16; k4 += 4) {
      float4 aA[4], aB[4], b[5];
#pragma unroll
      for (int u = 0; u < 4; ++u) {
        aA[u] = *(const float4*)&As[k4 + u][ty * 8];
        aB[u] = *(const float4*)&As[k4 + u][ty * 8 + 4];
      }
#pragma unroll
      for (int j = 0; j < 5; ++j) b[j] = *(const float4*)&BT[tx * 5 + j][kc + k4];
#pragma unroll
      for (int u = 0; u < 4; ++u) {
        float av[8] = {aA[u].x, aA[u].y, aA[u].z, aA[u].w,
                       aB[u].x, aB[u].y, aB[u].z, aB[u].w};
        float bv[5] = {((const float*)&b[0])[u], ((const float*)&b[1])[u],
                       ((const float*)&b[2])[u], ((const float*)&b[3])[u],
                       ((const float*)&b[4])[u]};
#pragma unroll
        for (int i = 0; i < 8; ++i)
#pragma unroll
          for (int j = 0; j < 5; ++j) acc[i][j] = fmaf(av[i], bv[j], acc[i][j]);
      }
    }
  }

#pragma unroll
  for (int i = 0; i < 8; ++i) {
    int r = ty * 8 + i;
    int grow = row0 + r;
    float vs = 0.f, vd = 0.f;
#pragma unroll
    for (int j = 0; j < 5; ++j) {
      vs = fmaf(acc[i][j], asv[tx * 5 + j], vs);
      vd = fmaf(acc[i][j], adv[tx * 5 + j], vd);
    }
#pragma unroll
    for (int off = 1; off < 8; off <<= 1) {
      vs += __shfl_xor(vs, off);
      vd += __shfl_xor(vd, off);
    }
    if (grow < N) {
#pragma unroll
      for (int j = 0; j < 5; ++j) h2[(size_t)grow * 40 + tx * 5 + j] = acc[i][j];
      if (tx == 0) { a_src2[grow] = vs; a_dst2[grow] = vd; }
    }
  }
}

// ---------------- agg2: wave per node, batched alpha, 4-deep MLP ----------------
__global__ __launch_bounds__(256) void agg2_kernel(const float* __restrict__ h2,
                                                   const float* __restrict__ a_src,
                                                   const float* __restrict__ a_dst,
                                                   const int* __restrict__ row_ptr,
                                                   const int* __restrict__ col,
                                                   const float* __restrict__ b2,
                                                   float* __restrict__ out, int N) {
  int lane = threadIdx.x & 63;
  int n = blockIdx.x * 4 + (threadIdx.x >> 6);
  if (n >= N) return;
  int beg = row_ptr[n], deg = row_ptr[n + 1] - beg;
  float adst = a_dst[n];
  float mx = -1e30f;
  for (int e0 = 0; e0 < deg; e0 += 64) {
    int e = e0 + lane;
    if (e < deg) mx = fmaxf(mx, lrelu(a_src[col[beg + e]] + adst));
  }
#pragma unroll
  for (int off = 1; off < 64; off <<= 1) mx = fmaxf(mx, __shfl_xor(mx, off));
  float sum = 0.f;
  for (int e0 = 0; e0 < deg; e0 += 64) {
    int e = e0 + lane;
    if (e < deg) sum += __expf(lrelu(a_src[col[beg + e]] + adst) - mx);
  }
#pragma unroll
  for (int off = 1; off < 64; off <<= 1) sum += __shfl_xor(sum, off);
  float invden = 1.f / (sum + 1e-16f);

  float acc = 0.f;
  for (int c0 = 0; c0 < deg; c0 += 64) {
    int eb = c0 + lane;
    int ec = eb < deg ? eb : deg - 1;
    int sB = col[beg + ec];
    float alB = 0.f;
    if (eb < deg) alB = __expf(lrelu(a_src[sB] + adst) - mx) * invden;
    int rem = deg - c0; if (rem > 64) rem = 64;
    for (int e = 0; e < rem; e += 4) {
#pragma unroll
      for (int u = 0; u < 4; ++u) {
        if (e + u < rem) {
          int s = __shfl(sB, e + u);
          float al = __shfl(alB, e + u);
          if (lane < 40) acc = fmaf(al, h2[(size_t)s * 40 + lane], acc);
        }
      }
    }
  }
  if (lane < 40) out[(size_t)n * 40 + lane] = acc + b2[lane];
}

extern "C" void kernel_launch(void* const* d_in, const int* in_sizes, int n_in,
                              void* d_out, int out_size, void* d_ws, size_t ws_size,
                              hipStream_t stream) {
  const float* x   = (const float*)d_in[0];
  const int*   ei  = (const int*)d_in[1];
  const float* W1  = (const float*)d_in[2];
  const float* as1 = (const float*)d_in[3];
  const float* ad1 = (const float*)d_in[4];
  const float* b1  = (const float*)d_in[5];
  const float* W2  = (const float*)d_in[6];
  const float* as2 = (const float*)d_in[7];
  const float* ad2 = (const float*)d_in[8];
  const float* b2  = (const float*)d_in[9];
  float* out = (float*)d_out;

  int N = in_sizes[0] / 256;
  int E = in_sizes[1] / 2;
  int Etot = E + N;

  char* p = (char*)d_ws;
  auto alloc = [&](size_t bytes) -> char* {
    char* r = p;
    p += (bytes + 255) & ~(size_t)255;
    return r;
  };
  unsigned short* xb    = (unsigned short*)alloc((size_t)N * 256 * 2);
  unsigned short* w1t   = (unsigned short*)alloc((size_t)256 * 256 * 2);
  unsigned short* h1b   = (unsigned short*)alloc((size_t)N * 256 * 2);
  unsigned short* hmidb = (unsigned short*)alloc((size_t)N * 256 * 2);
  float* a_src1 = (float*)alloc((size_t)N * 8 * 4);
  float* a_dst1 = (float*)alloc((size_t)N * 8 * 4);
  float* h2     = (float*)alloc((size_t)N * 40 * 4);
  float* a_src2 = (float*)alloc((size_t)N * 4);
  float* a_dst2 = (float*)alloc((size_t)N * 4);
  int* cnt      = (int*)alloc((size_t)N * 4);
  int* cursor   = (int*)alloc((size_t)N * 4);
  int* row_ptr  = (int*)alloc(((size_t)N + 1) * 4);
  int* tmp      = (int*)alloc((size_t)N * 4);
  int* bsum     = (int*)alloc(512);
  int* boff     = (int*)alloc(512);
  int* colx     = (int*)alloc((size_t)Etot * 4);

  hipMemsetAsync(cnt, 0, (size_t)N * 4, stream);

  int nbE = (Etot + 255) / 256;
  int nb1 = (N + 1023) / 1024;
  count_kernel<<<nbE, 256, 0, stream>>>(ei, cnt, E, N);
  scan1_kernel<<<nb1, 256, 0, stream>>>(cnt, tmp, bsum, N);
  scan2_kernel<<<1, 128, 0, stream>>>(bsum, boff, nb1);
  scan3_kernel<<<(N + 255) / 256, 256, 0, stream>>>(tmp, boff, row_ptr, cursor, N, Etot);
  fill_kernel<<<nbE, 256, 0, stream>>>(ei, cursor, colx, E, N);

  conv_x_kernel<<<(N * 64 + 255) / 256, 256, 0, stream>>>(x, xb, N * 64);
  conv_w_kernel<<<256, 256, 0, stream>>>(W1, w1t);
  gemm1_mfma_kernel<<<((N + 127) / 128) * 2, 256, 0, stream>>>(xb, w1t, h1b, N);
  att1_kernel<<<(N * 8 + 255) / 256, 256, 0, stream>>>(h1b, as1, ad1, a_src1, a_dst1, N);
  agg1_kernel<<<(N + 3) / 4, 256, 0, stream>>>(h1b, a_src1, a_dst1, row_ptr, colx, b1, hmidb, N);
  gemm2_kernel<<<(N + 255) / 256, 256, 0, stream>>>(hmidb, W2, as2, ad2, h2, a_src2, a_dst2, N);
  agg2_kernel<<<(N + 3) / 4, 256, 0, stream>>>(h2, a_src2, a_dst2, row_ptr, colx, b2, out, N);
}

// Round 5
// 465.318 us; speedup vs baseline: 1.8746x; 1.2180x over previous
//
#include <hip/hip_runtime.h>
#include <math.h>

#define NSLOPE 0.2f

__device__ __forceinline__ float lrelu(float x){ return x > 0.f ? x : NSLOPE * x; }
__device__ __forceinline__ float eluf(float x){ return x > 0.f ? x : expm1f(x); }

__device__ __forceinline__ unsigned short f2bf(float f) {
  unsigned u = __float_as_uint(f);
  u = (u + 0x7fff + ((u >> 16) & 1)) >> 16;   // RNE
  return (unsigned short)u;
}
__device__ __forceinline__ unsigned pk2bf(float a, float b) {
  return (unsigned)f2bf(a) | ((unsigned)f2bf(b) << 16);
}

typedef __attribute__((ext_vector_type(8))) short bf16x8;
typedef __attribute__((ext_vector_type(4))) float f32x4;

// W1[k][n] fp32 -> w1t[n][k] bf16 (256x256)
__global__ __launch_bounds__(256) void conv_w_kernel(const float* __restrict__ W,
                                                     unsigned short* __restrict__ wt) {
  int n = blockIdx.x;      // 0..255
  int k = threadIdx.x;     // 0..255
  wt[n * 256 + k] = f2bf(W[k * 256 + n]);
}

// ---------------- GEMM1 (MFMA): h1b[N,256] = bf16(x[N,256]) @ W1 ----------------
// x read directly as fp32, converted to bf16 during staging.
__global__ __launch_bounds__(256) void gemm1_mfma_kernel(const float* __restrict__ x,
                                                         const unsigned short* __restrict__ wt,
                                                         unsigned short* __restrict__ h1b,
                                                         int N) {
  __shared__ __align__(16) unsigned short Asl[128][40];  // [m][k], pitch 80B
  __shared__ __align__(16) unsigned short Bsl[128][40];  // [n][k]
  int tid = threadIdx.x;
  int bm = blockIdx.x >> 1, bn = blockIdx.x & 1;
  int row0 = bm * 128, col0 = bn * 128;

  int lr = tid >> 2;             // 0..63
  int lk = (tid & 3) * 8;        // element offset (8 elems)

  int lane = tid & 63, wv = tid >> 6;
  int m0 = (wv & 1) * 64, n0 = (wv >> 1) * 64;
  int lm = lane & 15, quad = lane >> 4;

  f32x4 acc[4][4];
#pragma unroll
  for (int i = 0; i < 4; ++i)
#pragma unroll
    for (int j = 0; j < 4; ++j) acc[i][j] = (f32x4){0.f, 0.f, 0.f, 0.f};

  for (int kc = 0; kc < 256; kc += 32) {
    float4 a0 = {0,0,0,0}, a1 = {0,0,0,0}, a2 = {0,0,0,0}, a3 = {0,0,0,0};
    int r0 = row0 + lr, r1 = row0 + 64 + lr;
    if (r0 < N) {
      const float4* s0 = (const float4*)(x + (size_t)r0 * 256 + kc + lk);
      a0 = s0[0]; a1 = s0[1];
    }
    if (r1 < N) {
      const float4* s1 = (const float4*)(x + (size_t)r1 * 256 + kc + lk);
      a2 = s1[0]; a3 = s1[1];
    }
    uint4 bv0 = *(const uint4*)(wt + (size_t)(col0 + lr) * 256 + kc + lk);
    uint4 bv1 = *(const uint4*)(wt + (size_t)(col0 + 64 + lr) * 256 + kc + lk);
    uint4 pa0, pa1;
    pa0.x = pk2bf(a0.x, a0.y); pa0.y = pk2bf(a0.z, a0.w);
    pa0.z = pk2bf(a1.x, a1.y); pa0.w = pk2bf(a1.z, a1.w);
    pa1.x = pk2bf(a2.x, a2.y); pa1.y = pk2bf(a2.z, a2.w);
    pa1.z = pk2bf(a3.x, a3.y); pa1.w = pk2bf(a3.z, a3.w);
    __syncthreads();
    *(uint4*)&Asl[lr][lk]      = pa0;
    *(uint4*)&Asl[64 + lr][lk] = pa1;
    *(uint4*)&Bsl[lr][lk]      = bv0;
    *(uint4*)&Bsl[64 + lr][lk] = bv1;
    __syncthreads();
    bf16x8 aF[4], bF[4];
#pragma unroll
    for (int i = 0; i < 4; ++i) aF[i] = *(const bf16x8*)&Asl[m0 + i * 16 + lm][quad * 8];
#pragma unroll
    for (int j = 0; j < 4; ++j) bF[j] = *(const bf16x8*)&Bsl[n0 + j * 16 + lm][quad * 8];
#pragma unroll
    for (int i = 0; i < 4; ++i)
#pragma unroll
      for (int j = 0; j < 4; ++j)
        acc[i][j] = __builtin_amdgcn_mfma_f32_16x16x32_bf16(aF[i], bF[j], acc[i][j], 0, 0, 0);
  }

#pragma unroll
  for (int i = 0; i < 4; ++i) {
#pragma unroll
    for (int j = 0; j < 4; ++j) {
      int gc = col0 + n0 + j * 16 + lm;
      int grb = row0 + m0 + i * 16 + quad * 4;
#pragma unroll
      for (int r = 0; r < 4; ++r) {
        int grow = grb + r;
        if (grow < N) h1b[(size_t)grow * 256 + gc] = f2bf(acc[i][j][r]);
      }
    }
  }
}

// ---------------- att1: a_src/a_dst [N,8] from bf16 h1 ----------------
__global__ __launch_bounds__(256) void att1_kernel(const unsigned short* __restrict__ h1b,
                                                   const float* __restrict__ att_src,
                                                   const float* __restrict__ att_dst,
                                                   float* __restrict__ a_src,
                                                   float* __restrict__ a_dst, int N) {
  __shared__ float sas[256];
  __shared__ float sad[256];
  int tid = threadIdx.x;
  sas[tid] = att_src[tid];
  sad[tid] = att_dst[tid];
  __syncthreads();
  int gid = blockIdx.x * 256 + tid;
  if (gid >= N * 8) return;
  int h = gid & 7;
  const uint4* hv = (const uint4*)(h1b + (size_t)(gid >> 3) * 256 + h * 32);
  float s1 = 0.f, s2 = 0.f;
#pragma unroll
  for (int q = 0; q < 4; ++q) {
    uint4 u = hv[q];
    unsigned uu[4] = {u.x, u.y, u.z, u.w};
#pragma unroll
    for (int e = 0; e < 4; ++e) {
      float lo = __uint_as_float(uu[e] << 16);
      float hi = __uint_as_float(uu[e] & 0xffff0000u);
      int c = h * 32 + q * 8 + e * 2;
      s1 += lo * sas[c] + hi * sas[c + 1];
      s2 += lo * sad[c] + hi * sad[c + 1];
    }
  }
  a_src[gid] = s1;
  a_dst[gid] = s2;
}

// ---------------- CSR build ----------------
__global__ void count_kernel(const int* __restrict__ ei, int* __restrict__ cnt, int E, int N) {
  int e = blockIdx.x * 256 + threadIdx.x;
  if (e >= E + N) return;
  int d = (e < E) ? ei[E + e] : (e - E);
  atomicAdd(&cnt[d], 1);
}

__global__ __launch_bounds__(256) void scan1_kernel(const int* __restrict__ cnt,
                                                    int* __restrict__ tmp,
                                                    int* __restrict__ bsum, int N) {
  __shared__ int sh[256];
  int t = threadIdx.x;
  int base = blockIdx.x * 1024 + t * 4;
  int v[4]; int s = 0;
#pragma unroll
  for (int j = 0; j < 4; ++j) { v[j] = (base + j < N) ? cnt[base + j] : 0; s += v[j]; }
  sh[t] = s;
  __syncthreads();
  for (int off = 1; off < 256; off <<= 1) {
    int xv = (t >= off) ? sh[t - off] : 0;
    __syncthreads();
    sh[t] += xv;
    __syncthreads();
  }
  if (t == 255) bsum[blockIdx.x] = sh[255];
  int run = sh[t] - s;  // exclusive
#pragma unroll
  for (int j = 0; j < 4; ++j) {
    if (base + j < N) tmp[base + j] = run;
    run += v[j];
  }
}

__global__ __launch_bounds__(128) void scan2_kernel(const int* __restrict__ bsum,
                                                    int* __restrict__ boff, int nb) {
  __shared__ int sh[128];
  int t = threadIdx.x;
  int v = (t < nb) ? bsum[t] : 0;
  sh[t] = v;
  __syncthreads();
  for (int off = 1; off < 128; off <<= 1) {
    int xv = (t >= off) ? sh[t - off] : 0;
    __syncthreads();
    sh[t] += xv;
    __syncthreads();
  }
  if (t < nb) boff[t] = sh[t] - v;
}

__global__ void scan3_kernel(const int* __restrict__ tmp, const int* __restrict__ boff,
                             int* __restrict__ row_ptr, int* __restrict__ cursor,
                             int N, int Etot) {
  int i = blockIdx.x * 256 + threadIdx.x;
  if (i == 0) row_ptr[N] = Etot;
  if (i >= N) return;
  int rp = tmp[i] + boff[i >> 10];
  row_ptr[i] = rp;
  cursor[i] = rp;
}

__global__ void fill_kernel(const int* __restrict__ ei, int* __restrict__ cursor,
                            int* __restrict__ col, int E, int N) {
  int e = blockIdx.x * 256 + threadIdx.x;
  if (e >= E + N) return;
  int s, d;
  if (e < E) { s = ei[e]; d = ei[E + e]; } else { s = e - E; d = s; }
  int pos = atomicAdd(&cursor[d], 1);
  col[pos] = s;
}

// ---------------- agg1: wave per node, no-max softmax, half-wave gather ----------------
__global__ __launch_bounds__(256) void agg1_kernel(const unsigned short* __restrict__ h1b,
                                                   const float* __restrict__ a_src,
                                                   const float* __restrict__ a_dst,
                                                   const int* __restrict__ row_ptr,
                                                   const int* __restrict__ col,
                                                   const float* __restrict__ b1,
                                                   unsigned short* __restrict__ hmidb, int N) {
  int lane = threadIdx.x & 63;
  int n = blockIdx.x * 4 + (threadIdx.x >> 6);
  if (n >= N) return;
  int beg = row_ptr[n], deg = row_ptr[n + 1] - beg;

  int hA = lane & 7, eoA = lane >> 3;
  float adst = a_dst[n * 8 + hA];
  // denominator (no max subtraction: |logit| <~ 10, exp safe in fp32)
  float den = 0.f;
  for (int e0 = 0; e0 < deg; e0 += 8) {
    int e = e0 + eoA;
    if (e < deg) den += __expf(lrelu(a_src[col[beg + e] * 8 + hA] + adst));
  }
#pragma unroll
  for (int off = 8; off < 64; off <<= 1) den += __shfl_xor(den, off);
  float invden = 1.f / (den + 1e-16f);

  int half = lane >> 5;     // 0: even edges, 1: odd edges
  int cl = lane & 31;       // channel group: channels cl*8 .. cl*8+7
  int hB = cl >> 2;         // head for this channel group
  float4 acc0 = {0.f,0.f,0.f,0.f}, acc1 = {0.f,0.f,0.f,0.f};

  for (int c0 = 0; c0 < deg; c0 += 8) {
    int eb = c0 + eoA;
    int ec = eb < deg ? eb : deg - 1;
    int sB = col[beg + ec];
    float alB = 0.f;
    if (eb < deg) alB = __expf(lrelu(a_src[sB * 8 + hA] + adst)) * invden;
    int rem = deg - c0; if (rem > 8) rem = 8;
#pragma unroll
    for (int p = 0; p < 4; ++p) {
      int myE = 2 * p + half;
      int s = __shfl(sB, myE * 8);
      float al = __shfl(alB, myE * 8 + hB);
      if (myE < rem) {
        uint4 hv = *(const uint4*)(h1b + (size_t)s * 256 + cl * 8);
        acc0.x = fmaf(al, __uint_as_float(hv.x << 16), acc0.x);
        acc0.y = fmaf(al, __uint_as_float(hv.x & 0xffff0000u), acc0.y);
        acc0.z = fmaf(al, __uint_as_float(hv.y << 16), acc0.z);
        acc0.w = fmaf(al, __uint_as_float(hv.y & 0xffff0000u), acc0.w);
        acc1.x = fmaf(al, __uint_as_float(hv.z << 16), acc1.x);
        acc1.y = fmaf(al, __uint_as_float(hv.z & 0xffff0000u), acc1.y);
        acc1.z = fmaf(al, __uint_as_float(hv.w << 16), acc1.z);
        acc1.w = fmaf(al, __uint_as_float(hv.w & 0xffff0000u), acc1.w);
      }
    }
  }
  float po[8] = {acc0.x, acc0.y, acc0.z, acc0.w, acc1.x, acc1.y, acc1.z, acc1.w};
#pragma unroll
  for (int j = 0; j < 8; ++j) po[j] += __shfl(po[j], cl + 32);
  if (half == 0) {
    const float4* b4 = (const float4*)(b1 + cl * 8);
    float4 bb0 = b4[0], bb1 = b4[1];
    float r0 = eluf(po[0] + bb0.x), r1 = eluf(po[1] + bb0.y);
    float r2 = eluf(po[2] + bb0.z), r3 = eluf(po[3] + bb0.w);
    float r4 = eluf(po[4] + bb1.x), r5 = eluf(po[5] + bb1.y);
    float r6 = eluf(po[6] + bb1.z), r7 = eluf(po[7] + bb1.w);
    uint4 ov;
    ov.x = pk2bf(r0, r1); ov.y = pk2bf(r2, r3);
    ov.z = pk2bf(r4, r5); ov.w = pk2bf(r6, r7);
    *(uint4*)(hmidb + (size_t)n * 256 + cl * 8) = ov;
  }
}

// ---------------- GEMM2 (MFMA) + att2: h2b[N,40](bf16) = hmid @ W2; dots fused ----------------
__global__ __launch_bounds__(256) void gemm2_mfma_kernel(const unsigned short* __restrict__ hmidb,
                                                         const float* __restrict__ W2,
                                                         const float* __restrict__ as2,
                                                         const float* __restrict__ ad2,
                                                         unsigned short* __restrict__ h2b,
                                                         float* __restrict__ a_src2,
                                                         float* __restrict__ a_dst2, int N) {
  __shared__ __align__(16) unsigned short Asl[128][40];   // [m][k-slice 32]
  __shared__ __align__(16) unsigned short Bs[48][264];    // W2^T bf16, [n][k], 16B-aligned pitch
  __shared__ float asv[48], adv[48];
  int tid = threadIdx.x;
  // zero Bs (covers pad cols 40-47), then fill
  for (int i = tid; i < 48 * 264 / 2; i += 256) ((unsigned*)Bs)[i] = 0;
  if (tid < 48) {
    asv[tid] = (tid < 40) ? as2[tid] : 0.f;
    adv[tid] = (tid < 40) ? ad2[tid] : 0.f;
  }
  __syncthreads();
  for (int i = tid; i < 256 * 40; i += 256) {
    int k = i / 40, c = i - k * 40;
    Bs[c][k] = f2bf(W2[i]);
  }

  int row0 = blockIdx.x * 128;
  int lane = tid & 63, wv = tid >> 6;
  int lm = lane & 15, quad = lane >> 4;
  int lr = tid >> 1;               // 0..127
  int lk = (tid & 1) * 16;         // 16 bf16 = 32B

  f32x4 acc[2][3];
#pragma unroll
  for (int i = 0; i < 2; ++i)
#pragma unroll
    for (int j = 0; j < 3; ++j) acc[i][j] = (f32x4){0.f,0.f,0.f,0.f};

  for (int kc = 0; kc < 256; kc += 32) {
    uint4 v0 = {0,0,0,0}, v1 = {0,0,0,0};
    int r = row0 + lr;
    if (r < N) {
      const uint4* src = (const uint4*)(hmidb + (size_t)r * 256 + kc + lk);
      v0 = src[0]; v1 = src[1];
    }
    __syncthreads();
    *(uint4*)&Asl[lr][lk]     = v0;
    *(uint4*)&Asl[lr][lk + 8] = v1;
    __syncthreads();
    bf16x8 aF[2], bF[3];
#pragma unroll
    for (int i = 0; i < 2; ++i) aF[i] = *(const bf16x8*)&Asl[wv * 32 + i * 16 + lm][quad * 8];
#pragma unroll
    for (int j = 0; j < 3; ++j) bF[j] = *(const bf16x8*)&Bs[j * 16 + lm][kc + quad * 8];
#pragma unroll
    for (int i = 0; i < 2; ++i)
#pragma unroll
      for (int j = 0; j < 3; ++j)
        acc[i][j] = __builtin_amdgcn_mfma_f32_16x16x32_bf16(aF[i], bF[j], acc[i][j], 0, 0, 0);
  }

#pragma unroll
  for (int i = 0; i < 2; ++i) {
#pragma unroll
    for (int r = 0; r < 4; ++r) {
      int grow = row0 + wv * 32 + i * 16 + quad * 4 + r;
      float vs = 0.f, vd = 0.f;
#pragma unroll
      for (int j = 0; j < 3; ++j) {
        vs = fmaf(acc[i][j][r], asv[j * 16 + lm], vs);
        vd = fmaf(acc[i][j][r], adv[j * 16 + lm], vd);
      }
#pragma unroll
      for (int off = 1; off < 16; off <<= 1) {
        vs += __shfl_xor(vs, off);
        vd += __shfl_xor(vd, off);
      }
      if (grow < N) {
#pragma unroll
        for (int j = 0; j < 3; ++j) {
          int c = j * 16 + lm;
          if (c < 40) h2b[(size_t)grow * 40 + c] = f2bf(acc[i][j][r]);
        }
        if (lm == 0) { a_src2[grow] = vs; a_dst2[grow] = vd; }
      }
    }
  }
}

// ---------------- agg2: wave per node, 6 edges x 10 lanes x uint2(4ch bf16) ----------------
__global__ __launch_bounds__(256) void agg2_kernel(const unsigned short* __restrict__ h2b,
                                                   const float* __restrict__ a_src,
                                                   const float* __restrict__ a_dst,
                                                   const int* __restrict__ row_ptr,
                                                   const int* __restrict__ col,
                                                   const float* __restrict__ b2,
                                                   float* __restrict__ out, int N) {
  int lane = threadIdx.x & 63;
  int n = blockIdx.x * 4 + (threadIdx.x >> 6);
  if (n >= N) return;
  int beg = row_ptr[n], deg = row_ptr[n + 1] - beg;
  float adst = a_dst[n];
  float den = 0.f;
  for (int e0 = 0; e0 < deg; e0 += 64) {
    int e = e0 + lane;
    if (e < deg) den += __expf(lrelu(a_src[col[beg + e]] + adst));
  }
#pragma unroll
  for (int off = 1; off < 64; off <<= 1) den += __shfl_xor(den, off);
  float invden = 1.f / (den + 1e-16f);

  int eg = lane / 10;        // 0..5 edge group (lanes 60-63 idle)
  int cg = lane % 10;        // channels cg*4 .. cg*4+3
  bool active = lane < 60;
  float4 acc = {0.f,0.f,0.f,0.f};
  for (int c0 = 0; c0 < deg; c0 += 6) {
    int e = c0 + eg;
    bool on = active && (e < deg);
    int ec = e < deg ? e : deg - 1;
    int s = col[beg + ec];
    if (on) {
      float al = __expf(lrelu(a_src[s] + adst)) * invden;
      uint2 hv = *(const uint2*)(h2b + (size_t)s * 40 + cg * 4);
      acc.x = fmaf(al, __uint_as_float(hv.x << 16), acc.x);
      acc.y = fmaf(al, __uint_as_float(hv.x & 0xffff0000u), acc.y);
      acc.z = fmaf(al, __uint_as_float(hv.y << 16), acc.z);
      acc.w = fmaf(al, __uint_as_float(hv.y & 0xffff0000u), acc.w);
    }
  }
  // sum the 6 edge groups: lanes cg, cg+10, ..., cg+50 (read original acc each step)
  float4 o = acc;
#pragma unroll
  for (int k = 1; k < 6; ++k) {
    int src = lane + 10 * k;
    o.x += __shfl(acc.x, src);
    o.y += __shfl(acc.y, src);
    o.z += __shfl(acc.z, src);
    o.w += __shfl(acc.w, src);
  }
  if (lane < 10) {
    float4 bb = *(const float4*)(b2 + cg * 4);
    o.x += bb.x; o.y += bb.y; o.z += bb.z; o.w += bb.w;
    *(float4*)(out + (size_t)n * 40 + cg * 4) = o;
  }
}

extern "C" void kernel_launch(void* const* d_in, const int* in_sizes, int n_in,
                              void* d_out, int out_size, void* d_ws, size_t ws_size,
                              hipStream_t stream) {
  const float* x   = (const float*)d_in[0];
  const int*   ei  = (const int*)d_in[1];
  const float* W1  = (const float*)d_in[2];
  const float* as1 = (const float*)d_in[3];
  const float* ad1 = (const float*)d_in[4];
  const float* b1  = (const float*)d_in[5];
  const float* W2  = (const float*)d_in[6];
  const float* as2 = (const float*)d_in[7];
  const float* ad2 = (const float*)d_in[8];
  const float* b2  = (const float*)d_in[9];
  float* out = (float*)d_out;

  int N = in_sizes[0] / 256;
  int E = in_sizes[1] / 2;
  int Etot = E + N;

  char* p = (char*)d_ws;
  auto alloc = [&](size_t bytes) -> char* {
    char* r = p;
    p += (bytes + 255) & ~(size_t)255;
    return r;
  };
  unsigned short* w1t   = (unsigned short*)alloc((size_t)256 * 256 * 2);
  unsigned short* h1b   = (unsigned short*)alloc((size_t)N * 256 * 2);
  unsigned short* hmidb = (unsigned short*)alloc((size_t)N * 256 * 2);
  unsigned short* h2b   = (unsigned short*)alloc((size_t)N * 40 * 2);
  float* a_src1 = (float*)alloc((size_t)N * 8 * 4);
  float* a_dst1 = (float*)alloc((size_t)N * 8 * 4);
  float* a_src2 = (float*)alloc((size_t)N * 4);
  float* a_dst2 = (float*)alloc((size_t)N * 4);
  int* cnt      = (int*)alloc((size_t)N * 4);
  int* cursor   = (int*)alloc((size_t)N * 4);
  int* row_ptr  = (int*)alloc(((size_t)N + 1) * 4);
  int* tmp      = (int*)alloc((size_t)N * 4);
  int* bsum     = (int*)alloc(512);
  int* boff     = (int*)alloc(512);
  int* colx     = (int*)alloc((size_t)Etot * 4);

  hipMemsetAsync(cnt, 0, (size_t)N * 4, stream);

  int nbE = (Etot + 255) / 256;
  int nb1 = (N + 1023) / 1024;
  count_kernel<<<nbE, 256, 0, stream>>>(ei, cnt, E, N);
  scan1_kernel<<<nb1, 256, 0, stream>>>(cnt, tmp, bsum, N);
  scan2_kernel<<<1, 128, 0, stream>>>(bsum, boff, nb1);
  scan3_kernel<<<(N + 255) / 256, 256, 0, stream>>>(tmp, boff, row_ptr, cursor, N, Etot);
  fill_kernel<<<nbE, 256, 0, stream>>>(ei, cursor, colx, E, N);

  conv_w_kernel<<<256, 256, 0, stream>>>(W1, w1t);
  gemm1_mfma_kernel<<<((N + 127) / 128) * 2, 256, 0, stream>>>(x, w1t, h1b, N);
  att1_kernel<<<(N * 8 + 255) / 256, 256, 0, stream>>>(h1b, as1, ad1, a_src1, a_dst1, N);
  agg1_kernel<<<(N + 3) / 4, 256, 0, stream>>>(h1b, a_src1, a_dst1, row_ptr, colx, b1, hmidb, N);
  gemm2_mfma_kernel<<<(N + 127) / 128, 256, 0, stream>>>(hmidb, W2, as2, ad2, h2b, a_src2, a_dst2, N);
  agg2_kernel<<<(N + 3) / 4, 256, 0, stream>>>(h2b, a_src2, a_dst2, row_ptr, colx, b2, out, N);
}